// Round 1
// baseline (1871.203 us; speedup 1.0000x reference)
//
#include <hip/hip_runtime.h>
#include <cmath>

// ---------------- problem constants ----------------
static constexpr float EPS = 1e-5f;
static constexpr float NEG = 0.2f;

// ---------------- CSR build ----------------
__global__ void count_kernel(const int* __restrict__ ei, int* __restrict__ cnt, int E) {
    int e = blockIdx.x * 256 + threadIdx.x;
    if (e < E) atomicAdd(&cnt[ei[E + e]], 1);
}

__global__ void scan_kernel(const int* __restrict__ cnt, int* __restrict__ rowptr, int n) {
    __shared__ int part[1024];
    int tid = threadIdx.x;
    int chunk = (n + 1023) >> 10;
    int s0 = tid * chunk;
    int s1 = s0 + chunk; if (s1 > n) s1 = n;
    int s = 0;
    for (int i = s0; i < s1; i++) s += cnt[i];
    part[tid] = s;
    __syncthreads();
    for (int off = 1; off < 1024; off <<= 1) {
        int v = (tid >= off) ? part[tid - off] : 0;
        __syncthreads();
        part[tid] += v;
        __syncthreads();
    }
    int run = (tid == 0) ? 0 : part[tid - 1];
    for (int i = s0; i < s1; i++) { rowptr[i] = run; run += cnt[i]; }
    if (tid == 1023) rowptr[n] = part[1023];
}

__global__ void prep_kernel(const int* __restrict__ rowptr, const int* __restrict__ cnt,
                            int* __restrict__ cursor, float* __restrict__ dis, int n) {
    int i = blockIdx.x * 256 + threadIdx.x;
    if (i < n) {
        cursor[i] = rowptr[i];
        dis[i] = rsqrtf((float)(cnt[i] + 1));   // +1 for self loop; always >= 1
    }
}

__global__ void fill_kernel(const int* __restrict__ ei, int* __restrict__ cursor,
                            int* __restrict__ col, int E) {
    int e = blockIdx.x * 256 + threadIdx.x;
    if (e < E) {
        int d = ei[E + e];
        int pos = atomicAdd(&cursor[d], 1);
        col[pos] = ei[e];
    }
}

// ---------------- dense GEMM: out[M,C] = A[M,K] @ W[K,C] (+bias) ----------------
template<int K, int C, int ACT>  // ACT: 0 none, 1 relu
__global__ __launch_bounds__(256) void gemm_kernel(const float* __restrict__ A,
                                                   const float* __restrict__ W,
                                                   const float* __restrict__ bias,
                                                   float* __restrict__ outp, int M) {
    __shared__ float lds[32 * K];
    int tid = threadIdx.x;
    int m0 = blockIdx.x * 32;
    for (int i = tid; i < 32 * K; i += 256) {
        int r = m0 + i / K;
        lds[i] = (r < M) ? A[(size_t)r * K + (i % K)] : 0.f;
    }
    __syncthreads();
    constexpr int C4 = C / 4;
    for (int u = tid; u < 32 * C4; u += 256) {
        int row = u / C4, c4 = (u % C4) * 4;
        int gr = m0 + row;
        if (gr >= M) continue;
        float ax = 0.f, ay = 0.f, az = 0.f, aw = 0.f;
        const float* ar = &lds[row * K];
        #pragma unroll 8
        for (int k = 0; k < K; k++) {
            float a = ar[k];
            float4 w = *reinterpret_cast<const float4*>(&W[(size_t)k * C + c4]);
            ax += a * w.x; ay += a * w.y; az += a * w.z; aw += a * w.w;
        }
        if (bias) {
            float4 b = *reinterpret_cast<const float4*>(&bias[c4]);
            ax += b.x; ay += b.y; az += b.z; aw += b.w;
        }
        if (ACT == 1) {
            ax = fmaxf(ax, 0.f); ay = fmaxf(ay, 0.f);
            az = fmaxf(az, 0.f); aw = fmaxf(aw, 0.f);
        }
        float4 r4; r4.x = ax; r4.y = ay; r4.z = az; r4.w = aw;
        *reinterpret_cast<float4*>(&outp[(size_t)gr * C + c4]) = r4;
    }
}

// ---------------- GCN propagate: out[d] = dis[d]*(dis[d]*xw[d] + sum_s dis[s]*xw[s]) + b ----------------
template<int C, int ACT>
__global__ void gcn_prop_kernel(const float* __restrict__ xw, const float* __restrict__ dis,
                                const int* __restrict__ rowptr, const int* __restrict__ col,
                                const float* __restrict__ bias, float* __restrict__ outp, int n) {
    int node = blockIdx.x;
    int c = threadIdx.x;
    float dd = dis[node];
    float acc = dd * xw[(size_t)node * C + c];
    int b0 = rowptr[node], b1 = rowptr[node + 1];
    for (int i = b0; i < b1; i++) {
        int s = col[i];
        acc += dis[s] * xw[(size_t)s * C + c];
    }
    float r = dd * acc + bias[c];
    if (ACT == 1) r = fmaxf(r, 0.f);
    outp[(size_t)node * C + c] = r;
}

// ---------------- alpha dot: as[n,h] = sum_c xh[n,h,c]*a_src[h,c] ----------------
template<int C>
__global__ void alpha_kernel(const float* __restrict__ xh, const float* __restrict__ a_src,
                             const float* __restrict__ a_dst, float* __restrict__ as_,
                             float* __restrict__ ad_, int n) {
    int wid = threadIdx.x >> 6, lane = threadIdx.x & 63;
    int node = blockIdx.x * 4 + wid;
    if (node >= n) return;
    const float* xr = xh + (size_t)node * 4 * C;
    float ps[4], pd[4];
    #pragma unroll
    for (int h = 0; h < 4; h++) {
        float v = xr[h * C + lane];
        ps[h] = v * a_src[h * C + lane];
        pd[h] = v * a_dst[h * C + lane];
        if (C == 128) {
            float v2 = xr[h * C + lane + 64];
            ps[h] += v2 * a_src[h * C + lane + 64];
            pd[h] += v2 * a_dst[h * C + lane + 64];
        }
    }
    #pragma unroll
    for (int o = 32; o; o >>= 1) {
        #pragma unroll
        for (int h = 0; h < 4; h++) {
            ps[h] += __shfl_xor(ps[h], o, 64);
            pd[h] += __shfl_xor(pd[h], o, 64);
        }
    }
    if (lane == 0) {
        #pragma unroll
        for (int h = 0; h < 4; h++) {
            as_[(size_t)node * 4 + h] = ps[h];
            ad_[(size_t)node * 4 + h] = pd[h];
        }
    }
}

// ---------------- GAT propagate (per-dst softmax, no atomics) ----------------
template<int C, bool CONCAT>
__global__ void gat_prop_kernel(const float* __restrict__ xh, const float* __restrict__ as_,
                                const float* __restrict__ ad_, const int* __restrict__ rowptr,
                                const int* __restrict__ col, const float* __restrict__ bias,
                                float* __restrict__ outp, int n) {
    constexpr int CAP = 256;
    constexpr int NW = C / 64;
    __shared__ float ex[(CAP + 1) * 4];
    __shared__ int scol[CAP + 1];
    __shared__ float wsum[NW][4];
    int node = blockIdx.x;
    int tid = threadIdx.x, lane = tid & 63, wid = tid >> 6;
    int b0 = rowptr[node];
    int cnt = rowptr[node + 1] - b0;
    float4 adv = *reinterpret_cast<const float4*>(&ad_[(size_t)node * 4]);
    float p0 = 0, p1 = 0, p2 = 0, p3 = 0;
    for (int i = tid; i <= cnt; i += C) {
        int s = (i == cnt) ? node : col[b0 + i];
        float4 asv = *reinterpret_cast<const float4*>(&as_[(size_t)s * 4]);
        float e0 = asv.x + adv.x; e0 = e0 > 0.f ? e0 : NEG * e0; float x0 = __expf(e0);
        float e1 = asv.y + adv.y; e1 = e1 > 0.f ? e1 : NEG * e1; float x1 = __expf(e1);
        float e2 = asv.z + adv.z; e2 = e2 > 0.f ? e2 : NEG * e2; float x2 = __expf(e2);
        float e3 = asv.w + adv.w; e3 = e3 > 0.f ? e3 : NEG * e3; float x3 = __expf(e3);
        if (i <= CAP) {
            ex[i * 4 + 0] = x0; ex[i * 4 + 1] = x1;
            ex[i * 4 + 2] = x2; ex[i * 4 + 3] = x3;
            scol[i] = s;
        }
        p0 += x0; p1 += x1; p2 += x2; p3 += x3;
    }
    #pragma unroll
    for (int o = 32; o; o >>= 1) {
        p0 += __shfl_xor(p0, o, 64); p1 += __shfl_xor(p1, o, 64);
        p2 += __shfl_xor(p2, o, 64); p3 += __shfl_xor(p3, o, 64);
    }
    if (lane == 0) { wsum[wid][0] = p0; wsum[wid][1] = p1; wsum[wid][2] = p2; wsum[wid][3] = p3; }
    __syncthreads();
    float d0 = 0, d1 = 0, d2 = 0, d3 = 0;
    #pragma unroll
    for (int w = 0; w < NW; w++) { d0 += wsum[w][0]; d1 += wsum[w][1]; d2 += wsum[w][2]; d3 += wsum[w][3]; }
    constexpr float SC = CONCAT ? 1.f : 0.25f;
    float s0 = SC / d0, s1 = SC / d1, s2 = SC / d2, s3 = SC / d3;

    float acc0 = 0, acc1 = 0, acc2 = 0, acc3 = 0;
    for (int i = 0; i <= cnt; i++) {
        int s; float w0, w1, w2, w3;
        if (i <= CAP) {
            s = scol[i];
            w0 = ex[i * 4 + 0] * s0; w1 = ex[i * 4 + 1] * s1;
            w2 = ex[i * 4 + 2] * s2; w3 = ex[i * 4 + 3] * s3;
        } else {
            s = (i == cnt) ? node : col[b0 + i];
            float4 asv = *reinterpret_cast<const float4*>(&as_[(size_t)s * 4]);
            float e0 = asv.x + adv.x; e0 = e0 > 0.f ? e0 : NEG * e0;
            float e1 = asv.y + adv.y; e1 = e1 > 0.f ? e1 : NEG * e1;
            float e2 = asv.z + adv.z; e2 = e2 > 0.f ? e2 : NEG * e2;
            float e3 = asv.w + adv.w; e3 = e3 > 0.f ? e3 : NEG * e3;
            w0 = __expf(e0) * s0; w1 = __expf(e1) * s1;
            w2 = __expf(e2) * s2; w3 = __expf(e3) * s3;
        }
        const float* xr = xh + (size_t)s * (4 * C);
        acc0 += w0 * xr[0 * C + tid];
        acc1 += w1 * xr[1 * C + tid];
        acc2 += w2 * xr[2 * C + tid];
        acc3 += w3 * xr[3 * C + tid];
    }
    if (CONCAT) {
        float r0 = acc0 + bias[0 * C + tid]; r0 = r0 > 0.f ? r0 : __expf(r0) - 1.f;
        float r1 = acc1 + bias[1 * C + tid]; r1 = r1 > 0.f ? r1 : __expf(r1) - 1.f;
        float r2 = acc2 + bias[2 * C + tid]; r2 = r2 > 0.f ? r2 : __expf(r2) - 1.f;
        float r3 = acc3 + bias[3 * C + tid]; r3 = r3 > 0.f ? r3 : __expf(r3) - 1.f;
        float* orow = outp + (size_t)node * 4 * C;
        orow[0 * C + tid] = r0; orow[1 * C + tid] = r1;
        orow[2 * C + tid] = r2; orow[3 * C + tid] = r3;
    } else {
        outp[(size_t)node * C + tid] = acc0 + acc1 + acc2 + acc3 + bias[tid];
    }
}

// ---------------- LayerNorm both branches -> cat buffer [n, 256] ----------------
__global__ void ln_kernel(const float* __restrict__ a_gcn, const float* __restrict__ a_gat,
                          const float* __restrict__ gw1, const float* __restrict__ gb1,
                          const float* __restrict__ gw2, const float* __restrict__ gb2,
                          float* __restrict__ catb, int n) {
    int node = blockIdx.x, tid = threadIdx.x, lane = tid & 63, wid = tid >> 6;
    __shared__ float ws2[2][2];
    #pragma unroll
    for (int half = 0; half < 2; half++) {
        const float* src = half ? a_gat : a_gcn;
        const float* gw = half ? gw2 : gw1;
        const float* gb = half ? gb2 : gb1;
        float v = src[(size_t)node * 128 + tid];
        float s = v, q = v * v;
        #pragma unroll
        for (int o = 32; o; o >>= 1) { s += __shfl_xor(s, o, 64); q += __shfl_xor(q, o, 64); }
        if (lane == 0) { ws2[wid][0] = s; ws2[wid][1] = q; }
        __syncthreads();
        float ts = ws2[0][0] + ws2[1][0], tq = ws2[0][1] + ws2[1][1];
        float mu = ts * (1.f / 128.f);
        float var = tq * (1.f / 128.f) - mu * mu;
        float r = (v - mu) * rsqrtf(var + EPS) * gw[tid] + gb[tid];
        catb[(size_t)node * 256 + half * 128 + tid] = r;
        __syncthreads();
    }
}

// ---------------- launch ----------------
extern "C" void kernel_launch(void* const* d_in, const int* in_sizes, int n_in,
                              void* d_out, int out_size, void* d_ws, size_t ws_size,
                              hipStream_t stream) {
    const float* x      = (const float*)d_in[0];
    const int*   ei     = (const int*)d_in[1];
    const float* W_gcn1 = (const float*)d_in[2];
    const float* b_gcn1 = (const float*)d_in[3];
    const float* W_gcn2 = (const float*)d_in[4];
    const float* b_gcn2 = (const float*)d_in[5];
    const float* W_gat1 = (const float*)d_in[6];
    const float* a_src1 = (const float*)d_in[7];
    const float* a_dst1 = (const float*)d_in[8];
    const float* b_gat1 = (const float*)d_in[9];
    const float* W_gat2 = (const float*)d_in[10];
    const float* a_src2 = (const float*)d_in[11];
    const float* a_dst2 = (const float*)d_in[12];
    const float* b_gat2 = (const float*)d_in[13];
    const float* g_gcn  = (const float*)d_in[14];
    const float* bt_gcn = (const float*)d_in[15];
    const float* g_gat  = (const float*)d_in[16];
    const float* bt_gat = (const float*)d_in[17];
    const float* W_fuse = (const float*)d_in[18];
    const float* b_fuse = (const float*)d_in[19];
    float* out = (float*)d_out;

    const int n = in_sizes[0] / 128;
    const int E = in_sizes[1] / 2;

    char* ws = (char*)d_ws;
    size_t off = 0;
    auto alloc = [&](size_t bytes) -> char* {
        char* p = ws + off;
        off += (bytes + 255) & ~(size_t)255;
        return p;
    };
    int*   cnt     = (int*)alloc((size_t)n * 4);
    int*   rowptr  = (int*)alloc((size_t)(n + 1) * 4);
    int*   cursor  = (int*)alloc((size_t)n * 4);
    int*   col     = (int*)alloc((size_t)E * 4);
    float* dis     = (float*)alloc((size_t)n * 4);
    float* as_     = (float*)alloc((size_t)n * 16);
    float* ad_     = (float*)alloc((size_t)n * 16);
    float* gcn_out = (float*)alloc((size_t)n * 128 * 4);
    float* P       = (float*)alloc((size_t)n * 512 * 4);   // xw1|h|xw2 -> xh1 -> xh2 -> cat
    float* G       = (float*)alloc((size_t)n * 256 * 4);   // g1 -> x_gat

    float* xw1  = P;
    float* h    = P + (size_t)n * 64;
    float* xw2  = P + (size_t)n * 128;
    float* xh1  = P;
    float* xh2  = P;
    float* catb = P;
    float* g1    = G;
    float* x_gat = G;

    // CSR build
    hipMemsetAsync(cnt, 0, (size_t)n * 4, stream);
    count_kernel<<<(E + 255) / 256, 256, 0, stream>>>(ei, cnt, E);
    scan_kernel<<<1, 1024, 0, stream>>>(cnt, rowptr, n);
    prep_kernel<<<(n + 255) / 256, 256, 0, stream>>>(rowptr, cnt, cursor, dis, n);
    fill_kernel<<<(E + 255) / 256, 256, 0, stream>>>(ei, cursor, col, E);

    int gbl = (n + 31) / 32;

    // GCN branch
    gemm_kernel<128, 64, 0><<<gbl, 256, 0, stream>>>(x, W_gcn1, nullptr, xw1, n);
    gcn_prop_kernel<64, 1><<<n, 64, 0, stream>>>(xw1, dis, rowptr, col, b_gcn1, h, n);
    gemm_kernel<64, 128, 0><<<gbl, 256, 0, stream>>>(h, W_gcn2, nullptr, xw2, n);
    gcn_prop_kernel<128, 0><<<n, 128, 0, stream>>>(xw2, dis, rowptr, col, b_gcn2, gcn_out, n);

    // GAT branch
    gemm_kernel<128, 256, 0><<<gbl, 256, 0, stream>>>(x, W_gat1, nullptr, xh1, n);
    alpha_kernel<64><<<(n + 3) / 4, 256, 0, stream>>>(xh1, a_src1, a_dst1, as_, ad_, n);
    gat_prop_kernel<64, true><<<n, 64, 0, stream>>>(xh1, as_, ad_, rowptr, col, b_gat1, g1, n);
    gemm_kernel<256, 512, 0><<<gbl, 256, 0, stream>>>(g1, W_gat2, nullptr, xh2, n);
    alpha_kernel<128><<<(n + 3) / 4, 256, 0, stream>>>(xh2, a_src2, a_dst2, as_, ad_, n);
    gat_prop_kernel<128, false><<<n, 128, 0, stream>>>(xh2, as_, ad_, rowptr, col, b_gat2, x_gat, n);

    // LN + concat + fuse
    ln_kernel<<<n, 128, 0, stream>>>(gcn_out, x_gat, g_gcn, bt_gcn, g_gat, bt_gat, catb, n);
    gemm_kernel<256, 128, 0><<<gbl, 256, 0, stream>>>(catb, W_fuse, b_fuse, out, n);
}

// Round 2
// 672.514 us; speedup vs baseline: 2.7824x; 2.7824x over previous
//
#include <hip/hip_runtime.h>
#include <cmath>

// ---------------- problem constants ----------------
static constexpr float EPS = 1e-5f;
static constexpr float NEG = 0.2f;

typedef __attribute__((ext_vector_type(8))) short short8v;
typedef __attribute__((ext_vector_type(4))) float f32x4;

__device__ inline unsigned short f2bf(float f) {
    union { float f; unsigned u; } v; v.f = f;
    unsigned r = v.u + 0x7FFF + ((v.u >> 16) & 1);   // RNE
    return (unsigned short)(r >> 16);
}

// ---------------- CSR build ----------------
__global__ void count_kernel(const int* __restrict__ ei, int* __restrict__ cnt, int E) {
    int e = blockIdx.x * 256 + threadIdx.x;
    if (e < E) atomicAdd(&cnt[ei[E + e]], 1);
}

__global__ void scan_kernel(const int* __restrict__ cnt, int* __restrict__ rowptr, int n) {
    __shared__ int part[1024];
    int tid = threadIdx.x;
    int chunk = (n + 1023) >> 10;
    int s0 = tid * chunk;
    int s1 = s0 + chunk; if (s1 > n) s1 = n;
    int s = 0;
    for (int i = s0; i < s1; i++) s += cnt[i];
    part[tid] = s;
    __syncthreads();
    for (int off = 1; off < 1024; off <<= 1) {
        int v = (tid >= off) ? part[tid - off] : 0;
        __syncthreads();
        part[tid] += v;
        __syncthreads();
    }
    int run = (tid == 0) ? 0 : part[tid - 1];
    for (int i = s0; i < s1; i++) { rowptr[i] = run; run += cnt[i]; }
    if (tid == 1023) rowptr[n] = part[1023];
}

__global__ void prep_kernel(const int* __restrict__ rowptr, const int* __restrict__ cnt,
                            int* __restrict__ cursor, float* __restrict__ dis, int n) {
    int i = blockIdx.x * 256 + threadIdx.x;
    if (i < n) {
        cursor[i] = rowptr[i];
        dis[i] = rsqrtf((float)(cnt[i] + 1));   // +1 for self loop; always >= 1
    }
}

__global__ void fill_kernel(const int* __restrict__ ei, int* __restrict__ cursor,
                            int* __restrict__ col, int E) {
    int e = blockIdx.x * 256 + threadIdx.x;
    if (e < E) {
        int d = ei[E + e];
        int pos = atomicAdd(&cursor[d], 1);
        col[pos] = ei[e];
    }
}

// ---------------- MFMA GEMM: out[M,C] = A[M,K] @ W[K,C] (+bias) ----------------
// bf16 inputs (converted during staging), fp32 accumulate.
// Tile: BM=128 x BN=64, BK=64. 4 waves, each owns 32x64 (2x4 16x16 frags).
// LDS XOR-swizzle: byte ^= (row&7)<<4 -> conflict-free ds_read_b128.
template<int K, int C, int ACT>
__global__ __launch_bounds__(256) void mfma_gemm(const float* __restrict__ A,
                                                 const float* __restrict__ W,
                                                 const float* __restrict__ bias,
                                                 float* __restrict__ outp, int M) {
    constexpr int BM = 128, BN = 64, BK = 64;
    __shared__ unsigned short As[BM * BK];   // [row][k] swizzled
    __shared__ unsigned short Ws[BN * BK];   // W^T [n][k] swizzled
    int tid = threadIdx.x;
    int wid = tid >> 6, lane = tid & 63;
    int m0 = blockIdx.x * BM;
    int n0 = blockIdx.y * BN;

    f32x4 acc[2][4] = {};

    for (int k0 = 0; k0 < K; k0 += BK) {
        // stage A: 128x64 bf16, thread does 8 float4 loads
        for (int i = tid; i < BM * (BK / 4); i += 256) {
            int row = i / (BK / 4);
            int kk = (i % (BK / 4)) * 4;
            int gr = m0 + row;
            float4 v = make_float4(0.f, 0.f, 0.f, 0.f);
            if (gr < M) v = *reinterpret_cast<const float4*>(&A[(size_t)gr * K + k0 + kk]);
            unsigned long long pk = (unsigned long long)f2bf(v.x)
                                  | ((unsigned long long)f2bf(v.y) << 16)
                                  | ((unsigned long long)f2bf(v.z) << 32)
                                  | ((unsigned long long)f2bf(v.w) << 48);
            int byte = (kk * 2) ^ ((row & 7) << 4);
            *reinterpret_cast<unsigned long long*>((char*)As + row * (BK * 2) + byte) = pk;
        }
        // stage W transposed: W[k0+kk][n0+nn..+3] -> Ws[n][k]
        for (int i = tid; i < BK * (BN / 4); i += 256) {
            int kk = i / (BN / 4);
            int nn = (i % (BN / 4)) * 4;
            float4 v = *reinterpret_cast<const float4*>(&W[(size_t)(k0 + kk) * C + n0 + nn]);
            #pragma unroll
            for (int j = 0; j < 4; j++) {
                int nrow = nn + j;
                int byte = (kk * 2) ^ ((nrow & 7) << 4);
                *reinterpret_cast<unsigned short*>((char*)Ws + nrow * (BK * 2) + byte) =
                    f2bf((&v.x)[j]);
            }
        }
        __syncthreads();
        #pragma unroll
        for (int kc = 0; kc < BK; kc += 32) {
            short8v afr[2], bfr[4];
            int kk = kc + (lane >> 4) * 8;
            #pragma unroll
            for (int mf = 0; mf < 2; mf++) {
                int row = wid * 32 + mf * 16 + (lane & 15);
                int byte = (kk * 2) ^ ((row & 7) << 4);
                afr[mf] = *reinterpret_cast<const short8v*>((char*)As + row * (BK * 2) + byte);
            }
            #pragma unroll
            for (int nf = 0; nf < 4; nf++) {
                int nrow = nf * 16 + (lane & 15);
                int byte = (kk * 2) ^ ((nrow & 7) << 4);
                bfr[nf] = *reinterpret_cast<const short8v*>((char*)Ws + nrow * (BK * 2) + byte);
            }
            #pragma unroll
            for (int mf = 0; mf < 2; mf++)
                #pragma unroll
                for (int nf = 0; nf < 4; nf++)
                    acc[mf][nf] = __builtin_amdgcn_mfma_f32_16x16x32_bf16(
                        afr[mf], bfr[nf], acc[mf][nf], 0, 0, 0);
        }
        __syncthreads();
    }
    // store: D row=(lane>>4)*4+r, col=lane&15 (verified layout)
    #pragma unroll
    for (int mf = 0; mf < 2; mf++) {
        #pragma unroll
        for (int nf = 0; nf < 4; nf++) {
            #pragma unroll
            for (int r = 0; r < 4; r++) {
                int row = m0 + wid * 32 + mf * 16 + (lane >> 4) * 4 + r;
                int colg = n0 + nf * 16 + (lane & 15);
                if (row < M) {
                    float v = acc[mf][nf][r];
                    if (bias) v += bias[colg];
                    if (ACT == 1) v = fmaxf(v, 0.f);
                    outp[(size_t)row * C + colg] = v;
                }
            }
        }
    }
}

// ---------------- GCN propagate ----------------
template<int C, int ACT>
__global__ void gcn_prop_kernel(const float* __restrict__ xw, const float* __restrict__ dis,
                                const int* __restrict__ rowptr, const int* __restrict__ col,
                                const float* __restrict__ bias, float* __restrict__ outp, int n) {
    int node = blockIdx.x;
    int c = threadIdx.x;
    float dd = dis[node];
    float acc = dd * xw[(size_t)node * C + c];
    int b0 = rowptr[node], b1 = rowptr[node + 1];
    for (int i = b0; i < b1; i++) {
        int s = col[i];
        acc += dis[s] * xw[(size_t)s * C + c];
    }
    float r = dd * acc + bias[c];
    if (ACT == 1) r = fmaxf(r, 0.f);
    outp[(size_t)node * C + c] = r;
}

// ---------------- alpha dot ----------------
template<int C>
__global__ void alpha_kernel(const float* __restrict__ xh, const float* __restrict__ a_src,
                             const float* __restrict__ a_dst, float* __restrict__ as_,
                             float* __restrict__ ad_, int n) {
    int wid = threadIdx.x >> 6, lane = threadIdx.x & 63;
    int node = blockIdx.x * 4 + wid;
    if (node >= n) return;
    const float* xr = xh + (size_t)node * 4 * C;
    float ps[4], pd[4];
    #pragma unroll
    for (int h = 0; h < 4; h++) {
        float v = xr[h * C + lane];
        ps[h] = v * a_src[h * C + lane];
        pd[h] = v * a_dst[h * C + lane];
        if (C == 128) {
            float v2 = xr[h * C + lane + 64];
            ps[h] += v2 * a_src[h * C + lane + 64];
            pd[h] += v2 * a_dst[h * C + lane + 64];
        }
    }
    #pragma unroll
    for (int o = 32; o; o >>= 1) {
        #pragma unroll
        for (int h = 0; h < 4; h++) {
            ps[h] += __shfl_xor(ps[h], o, 64);
            pd[h] += __shfl_xor(pd[h], o, 64);
        }
    }
    if (lane == 0) {
        #pragma unroll
        for (int h = 0; h < 4; h++) {
            as_[(size_t)node * 4 + h] = ps[h];
            ad_[(size_t)node * 4 + h] = pd[h];
        }
    }
}

// ---------------- GAT propagate (per-dst softmax, no atomics) ----------------
template<int C, bool CONCAT>
__global__ void gat_prop_kernel(const float* __restrict__ xh, const float* __restrict__ as_,
                                const float* __restrict__ ad_, const int* __restrict__ rowptr,
                                const int* __restrict__ col, const float* __restrict__ bias,
                                float* __restrict__ outp, int n) {
    constexpr int CAP = 256;
    constexpr int NW = C / 64;
    __shared__ float ex[(CAP + 1) * 4];
    __shared__ int scol[CAP + 1];
    __shared__ float wsum[NW][4];
    int node = blockIdx.x;
    int tid = threadIdx.x, lane = tid & 63, wid = tid >> 6;
    int b0 = rowptr[node];
    int cnt = rowptr[node + 1] - b0;
    float4 adv = *reinterpret_cast<const float4*>(&ad_[(size_t)node * 4]);
    float p0 = 0, p1 = 0, p2 = 0, p3 = 0;
    for (int i = tid; i <= cnt; i += C) {
        int s = (i == cnt) ? node : col[b0 + i];
        float4 asv = *reinterpret_cast<const float4*>(&as_[(size_t)s * 4]);
        float e0 = asv.x + adv.x; e0 = e0 > 0.f ? e0 : NEG * e0; float x0 = __expf(e0);
        float e1 = asv.y + adv.y; e1 = e1 > 0.f ? e1 : NEG * e1; float x1 = __expf(e1);
        float e2 = asv.z + adv.z; e2 = e2 > 0.f ? e2 : NEG * e2; float x2 = __expf(e2);
        float e3 = asv.w + adv.w; e3 = e3 > 0.f ? e3 : NEG * e3; float x3 = __expf(e3);
        if (i <= CAP) {
            ex[i * 4 + 0] = x0; ex[i * 4 + 1] = x1;
            ex[i * 4 + 2] = x2; ex[i * 4 + 3] = x3;
            scol[i] = s;
        }
        p0 += x0; p1 += x1; p2 += x2; p3 += x3;
    }
    #pragma unroll
    for (int o = 32; o; o >>= 1) {
        p0 += __shfl_xor(p0, o, 64); p1 += __shfl_xor(p1, o, 64);
        p2 += __shfl_xor(p2, o, 64); p3 += __shfl_xor(p3, o, 64);
    }
    if (lane == 0) { wsum[wid][0] = p0; wsum[wid][1] = p1; wsum[wid][2] = p2; wsum[wid][3] = p3; }
    __syncthreads();
    float d0 = 0, d1 = 0, d2 = 0, d3 = 0;
    #pragma unroll
    for (int w = 0; w < NW; w++) { d0 += wsum[w][0]; d1 += wsum[w][1]; d2 += wsum[w][2]; d3 += wsum[w][3]; }
    constexpr float SC = CONCAT ? 1.f : 0.25f;
    float s0 = SC / d0, s1 = SC / d1, s2 = SC / d2, s3 = SC / d3;

    float acc0 = 0, acc1 = 0, acc2 = 0, acc3 = 0;
    for (int i = 0; i <= cnt; i++) {
        int s; float w0, w1, w2, w3;
        if (i <= CAP) {
            s = scol[i];
            w0 = ex[i * 4 + 0] * s0; w1 = ex[i * 4 + 1] * s1;
            w2 = ex[i * 4 + 2] * s2; w3 = ex[i * 4 + 3] * s3;
        } else {
            s = (i == cnt) ? node : col[b0 + i];
            float4 asv = *reinterpret_cast<const float4*>(&as_[(size_t)s * 4]);
            float e0 = asv.x + adv.x; e0 = e0 > 0.f ? e0 : NEG * e0;
            float e1 = asv.y + adv.y; e1 = e1 > 0.f ? e1 : NEG * e1;
            float e2 = asv.z + adv.z; e2 = e2 > 0.f ? e2 : NEG * e2;
            float e3 = asv.w + adv.w; e3 = e3 > 0.f ? e3 : NEG * e3;
            w0 = __expf(e0) * s0; w1 = __expf(e1) * s1;
            w2 = __expf(e2) * s2; w3 = __expf(e3) * s3;
        }
        const float* xr = xh + (size_t)s * (4 * C);
        acc0 += w0 * xr[0 * C + tid];
        acc1 += w1 * xr[1 * C + tid];
        acc2 += w2 * xr[2 * C + tid];
        acc3 += w3 * xr[3 * C + tid];
    }
    if (CONCAT) {
        float r0 = acc0 + bias[0 * C + tid]; r0 = r0 > 0.f ? r0 : __expf(r0) - 1.f;
        float r1 = acc1 + bias[1 * C + tid]; r1 = r1 > 0.f ? r1 : __expf(r1) - 1.f;
        float r2 = acc2 + bias[2 * C + tid]; r2 = r2 > 0.f ? r2 : __expf(r2) - 1.f;
        float r3 = acc3 + bias[3 * C + tid]; r3 = r3 > 0.f ? r3 : __expf(r3) - 1.f;
        float* orow = outp + (size_t)node * 4 * C;
        orow[0 * C + tid] = r0; orow[1 * C + tid] = r1;
        orow[2 * C + tid] = r2; orow[3 * C + tid] = r3;
    } else {
        outp[(size_t)node * C + tid] = acc0 + acc1 + acc2 + acc3 + bias[tid];
    }
}

// ---------------- LayerNorm both branches -> cat buffer [n, 256] ----------------
__global__ void ln_kernel(const float* __restrict__ a_gcn, const float* __restrict__ a_gat,
                          const float* __restrict__ gw1, const float* __restrict__ gb1,
                          const float* __restrict__ gw2, const float* __restrict__ gb2,
                          float* __restrict__ catb, int n) {
    int node = blockIdx.x, tid = threadIdx.x, lane = tid & 63, wid = tid >> 6;
    __shared__ float ws2[2][2];
    #pragma unroll
    for (int half = 0; half < 2; half++) {
        const float* src = half ? a_gat : a_gcn;
        const float* gw = half ? gw2 : gw1;
        const float* gb = half ? gb2 : gb1;
        float v = src[(size_t)node * 128 + tid];
        float s = v, q = v * v;
        #pragma unroll
        for (int o = 32; o; o >>= 1) { s += __shfl_xor(s, o, 64); q += __shfl_xor(q, o, 64); }
        if (lane == 0) { ws2[wid][0] = s; ws2[wid][1] = q; }
        __syncthreads();
        float ts = ws2[0][0] + ws2[1][0], tq = ws2[0][1] + ws2[1][1];
        float mu = ts * (1.f / 128.f);
        float var = tq * (1.f / 128.f) - mu * mu;
        float r = (v - mu) * rsqrtf(var + EPS) * gw[tid] + gb[tid];
        catb[(size_t)node * 256 + half * 128 + tid] = r;
        __syncthreads();
    }
}

// ---------------- launch ----------------
extern "C" void kernel_launch(void* const* d_in, const int* in_sizes, int n_in,
                              void* d_out, int out_size, void* d_ws, size_t ws_size,
                              hipStream_t stream) {
    const float* x      = (const float*)d_in[0];
    const int*   ei     = (const int*)d_in[1];
    const float* W_gcn1 = (const float*)d_in[2];
    const float* b_gcn1 = (const float*)d_in[3];
    const float* W_gcn2 = (const float*)d_in[4];
    const float* b_gcn2 = (const float*)d_in[5];
    const float* W_gat1 = (const float*)d_in[6];
    const float* a_src1 = (const float*)d_in[7];
    const float* a_dst1 = (const float*)d_in[8];
    const float* b_gat1 = (const float*)d_in[9];
    const float* W_gat2 = (const float*)d_in[10];
    const float* a_src2 = (const float*)d_in[11];
    const float* a_dst2 = (const float*)d_in[12];
    const float* b_gat2 = (const float*)d_in[13];
    const float* g_gcn  = (const float*)d_in[14];
    const float* bt_gcn = (const float*)d_in[15];
    const float* g_gat  = (const float*)d_in[16];
    const float* bt_gat = (const float*)d_in[17];
    const float* W_fuse = (const float*)d_in[18];
    const float* b_fuse = (const float*)d_in[19];
    float* out = (float*)d_out;

    const int n = in_sizes[0] / 128;
    const int E = in_sizes[1] / 2;

    char* ws = (char*)d_ws;
    size_t off = 0;
    auto alloc = [&](size_t bytes) -> char* {
        char* p = ws + off;
        off += (bytes + 255) & ~(size_t)255;
        return p;
    };
    int*   cnt     = (int*)alloc((size_t)n * 4);
    int*   rowptr  = (int*)alloc((size_t)(n + 1) * 4);
    int*   cursor  = (int*)alloc((size_t)n * 4);
    int*   col     = (int*)alloc((size_t)E * 4);
    float* dis     = (float*)alloc((size_t)n * 4);
    float* as_     = (float*)alloc((size_t)n * 16);
    float* ad_     = (float*)alloc((size_t)n * 16);
    float* gcn_out = (float*)alloc((size_t)n * 128 * 4);
    float* P       = (float*)alloc((size_t)n * 512 * 4);   // xw1|h|xw2 -> xh1 -> xh2 -> cat
    float* G       = (float*)alloc((size_t)n * 256 * 4);   // g1 -> x_gat

    float* xw1  = P;
    float* h    = P + (size_t)n * 64;
    float* xw2  = P + (size_t)n * 128;
    float* xh1  = P;
    float* xh2  = P;
    float* catb = P;
    float* g1    = G;
    float* x_gat = G;

    // CSR build
    hipMemsetAsync(cnt, 0, (size_t)n * 4, stream);
    count_kernel<<<(E + 255) / 256, 256, 0, stream>>>(ei, cnt, E);
    scan_kernel<<<1, 1024, 0, stream>>>(cnt, rowptr, n);
    prep_kernel<<<(n + 255) / 256, 256, 0, stream>>>(rowptr, cnt, cursor, dis, n);
    fill_kernel<<<(E + 255) / 256, 256, 0, stream>>>(ei, cursor, col, E);

    int gm = (n + 127) / 128;

    // GCN branch
    mfma_gemm<128, 64, 0><<<dim3(gm, 1), 256, 0, stream>>>(x, W_gcn1, nullptr, xw1, n);
    gcn_prop_kernel<64, 1><<<n, 64, 0, stream>>>(xw1, dis, rowptr, col, b_gcn1, h, n);
    mfma_gemm<64, 128, 0><<<dim3(gm, 2), 256, 0, stream>>>(h, W_gcn2, nullptr, xw2, n);
    gcn_prop_kernel<128, 0><<<n, 128, 0, stream>>>(xw2, dis, rowptr, col, b_gcn2, gcn_out, n);

    // GAT branch
    mfma_gemm<128, 256, 0><<<dim3(gm, 4), 256, 0, stream>>>(x, W_gat1, nullptr, xh1, n);
    alpha_kernel<64><<<(n + 3) / 4, 256, 0, stream>>>(xh1, a_src1, a_dst1, as_, ad_, n);
    gat_prop_kernel<64, true><<<n, 64, 0, stream>>>(xh1, as_, ad_, rowptr, col, b_gat1, g1, n);
    mfma_gemm<256, 512, 0><<<dim3(gm, 8), 256, 0, stream>>>(g1, W_gat2, nullptr, xh2, n);
    alpha_kernel<128><<<(n + 3) / 4, 256, 0, stream>>>(xh2, a_src2, a_dst2, as_, ad_, n);
    gat_prop_kernel<128, false><<<n, 128, 0, stream>>>(xh2, as_, ad_, rowptr, col, b_gat2, x_gat, n);

    // LN + concat + fuse
    ln_kernel<<<n, 128, 0, stream>>>(gcn_out, x_gat, g_gcn, bt_gcn, g_gat, bt_gat, catb, n);
    mfma_gemm<256, 128, 0><<<dim3(gm, 2), 256, 0, stream>>>(catb, W_fuse, b_fuse, out, n);
}

// Round 3
// 536.213 us; speedup vs baseline: 3.4897x; 1.2542x over previous
//
#include <hip/hip_runtime.h>
#include <cmath>

// ---------------- problem constants ----------------
static constexpr float EPS = 1e-5f;
static constexpr float NEG = 0.2f;

typedef __attribute__((ext_vector_type(8))) short short8v;
typedef __attribute__((ext_vector_type(4))) float f32x4;

__device__ inline unsigned short f2bf(float f) {
    union { float f; unsigned u; } v; v.f = f;
    unsigned r = v.u + 0x7FFF + ((v.u >> 16) & 1);   // RNE
    return (unsigned short)(r >> 16);
}
__device__ inline float bf2f(unsigned short u) {
    union { unsigned u; float f; } v; v.u = (unsigned)u << 16; return v.f;
}

// ---------------- CSR build ----------------
__global__ void count_kernel(const int* __restrict__ ei, int* __restrict__ cnt, int E) {
    int e = blockIdx.x * 256 + threadIdx.x;
    if (e < E) atomicAdd(&cnt[ei[E + e]], 1);
}

__global__ void scan_kernel(const int* __restrict__ cnt, int* __restrict__ rowptr, int n) {
    __shared__ int part[1024];
    int tid = threadIdx.x;
    int chunk = (n + 1023) >> 10;
    int s0 = tid * chunk;
    int s1 = s0 + chunk; if (s1 > n) s1 = n;
    int s = 0;
    for (int i = s0; i < s1; i++) s += cnt[i];
    part[tid] = s;
    __syncthreads();
    for (int off = 1; off < 1024; off <<= 1) {
        int v = (tid >= off) ? part[tid - off] : 0;
        __syncthreads();
        part[tid] += v;
        __syncthreads();
    }
    int run = (tid == 0) ? 0 : part[tid - 1];
    for (int i = s0; i < s1; i++) { rowptr[i] = run; run += cnt[i]; }
    if (tid == 1023) rowptr[n] = part[1023];
}

__global__ void prep_kernel(const int* __restrict__ rowptr, const int* __restrict__ cnt,
                            int* __restrict__ cursor, float* __restrict__ dis, int n) {
    int i = blockIdx.x * 256 + threadIdx.x;
    if (i < n) {
        cursor[i] = rowptr[i];
        dis[i] = rsqrtf((float)(cnt[i] + 1));
    }
}

__global__ void fill_kernel(const int* __restrict__ ei, int* __restrict__ cursor,
                            int* __restrict__ col, int E) {
    int e = blockIdx.x * 256 + threadIdx.x;
    if (e < E) {
        int d = ei[E + e];
        int pos = atomicAdd(&cursor[d], 1);
        col[pos] = ei[e];
    }
}

// ---------------- MFMA GEMM: out[M,C] = A[M,K] @ W[K,C] (+bias) ----------------
// A: fp32 or bf16 (ABF). out: fp32 or bf16 (OBF). fp32 accumulate.
// Tile: BM=128 x BN=64, BK=64. 4 waves, each 32x64 (2x4 16x16 frags).
// LDS XOR-swizzle: byte ^= (row&7)<<4.
template<int K, int C, bool ABF, bool OBF>
__global__ __launch_bounds__(256) void mfma_gemm(const void* __restrict__ Ap,
                                                 const float* __restrict__ W,
                                                 const float* __restrict__ bias,
                                                 void* __restrict__ outp, int M) {
    constexpr int BM = 128, BN = 64, BK = 64;
    __shared__ unsigned short As[BM * BK];
    __shared__ unsigned short Ws[BN * BK];
    int tid = threadIdx.x;
    int wid = tid >> 6, lane = tid & 63;
    int m0 = blockIdx.x * BM;
    int n0 = blockIdx.y * BN;

    f32x4 acc[2][4] = {};

    for (int k0 = 0; k0 < K; k0 += BK) {
        if constexpr (ABF) {
            const unsigned short* A = (const unsigned short*)Ap;
            for (int i = tid; i < BM * (BK / 8); i += 256) {
                int row = i / (BK / 8);
                int kk = (i % (BK / 8)) * 8;
                int gr = m0 + row;
                short8v v = short8v{0, 0, 0, 0, 0, 0, 0, 0};
                if (gr < M) v = *reinterpret_cast<const short8v*>(&A[(size_t)gr * K + k0 + kk]);
                int byte = (kk * 2) ^ ((row & 7) << 4);
                *reinterpret_cast<short8v*>((char*)As + row * (BK * 2) + byte) = v;
            }
        } else {
            const float* A = (const float*)Ap;
            for (int i = tid; i < BM * (BK / 4); i += 256) {
                int row = i / (BK / 4);
                int kk = (i % (BK / 4)) * 4;
                int gr = m0 + row;
                float4 v = make_float4(0.f, 0.f, 0.f, 0.f);
                if (gr < M) v = *reinterpret_cast<const float4*>(&A[(size_t)gr * K + k0 + kk]);
                unsigned long long pk = (unsigned long long)f2bf(v.x)
                                      | ((unsigned long long)f2bf(v.y) << 16)
                                      | ((unsigned long long)f2bf(v.z) << 32)
                                      | ((unsigned long long)f2bf(v.w) << 48);
                int byte = (kk * 2) ^ ((row & 7) << 4);
                *reinterpret_cast<unsigned long long*>((char*)As + row * (BK * 2) + byte) = pk;
            }
        }
        // stage W transposed: W[k0+kk][n0+nn..+3] -> Ws[n][k]
        for (int i = tid; i < BK * (BN / 4); i += 256) {
            int kk = i / (BN / 4);
            int nn = (i % (BN / 4)) * 4;
            float4 v = *reinterpret_cast<const float4*>(&W[(size_t)(k0 + kk) * C + n0 + nn]);
            #pragma unroll
            for (int j = 0; j < 4; j++) {
                int nrow = nn + j;
                int byte = (kk * 2) ^ ((nrow & 7) << 4);
                *reinterpret_cast<unsigned short*>((char*)Ws + nrow * (BK * 2) + byte) =
                    f2bf((&v.x)[j]);
            }
        }
        __syncthreads();
        #pragma unroll
        for (int kc = 0; kc < BK; kc += 32) {
            short8v afr[2], bfr[4];
            int kk = kc + (lane >> 4) * 8;
            #pragma unroll
            for (int mf = 0; mf < 2; mf++) {
                int row = wid * 32 + mf * 16 + (lane & 15);
                int byte = (kk * 2) ^ ((row & 7) << 4);
                afr[mf] = *reinterpret_cast<const short8v*>((char*)As + row * (BK * 2) + byte);
            }
            #pragma unroll
            for (int nf = 0; nf < 4; nf++) {
                int nrow = nf * 16 + (lane & 15);
                int byte = (kk * 2) ^ ((nrow & 7) << 4);
                bfr[nf] = *reinterpret_cast<const short8v*>((char*)Ws + nrow * (BK * 2) + byte);
            }
            #pragma unroll
            for (int mf = 0; mf < 2; mf++)
                #pragma unroll
                for (int nf = 0; nf < 4; nf++)
                    acc[mf][nf] = __builtin_amdgcn_mfma_f32_16x16x32_bf16(
                        afr[mf], bfr[nf], acc[mf][nf], 0, 0, 0);
        }
        __syncthreads();
    }
    #pragma unroll
    for (int mf = 0; mf < 2; mf++) {
        #pragma unroll
        for (int nf = 0; nf < 4; nf++) {
            #pragma unroll
            for (int r = 0; r < 4; r++) {
                int row = m0 + wid * 32 + mf * 16 + (lane >> 4) * 4 + r;
                int colg = n0 + nf * 16 + (lane & 15);
                if (row < M) {
                    float v = acc[mf][nf][r];
                    if (bias) v += bias[colg];
                    if constexpr (OBF)
                        ((unsigned short*)outp)[(size_t)row * C + colg] = f2bf(v);
                    else
                        ((float*)outp)[(size_t)row * C + colg] = v;
                }
            }
        }
    }
}

// ---------------- GCN propagate (bf16 features in, bf16/fp32 out) ----------------
template<int C, int ACT, bool OBF>
__global__ void gcn_prop_kernel(const unsigned short* __restrict__ xw, const float* __restrict__ dis,
                                const int* __restrict__ rowptr, const int* __restrict__ col,
                                const float* __restrict__ bias, void* __restrict__ outp, int n) {
    int node = blockIdx.x;
    int c = threadIdx.x;
    float dd = dis[node];
    float acc = dd * bf2f(xw[(size_t)node * C + c]);
    int b0 = rowptr[node], b1 = rowptr[node + 1];
    for (int i = b0; i < b1; i++) {
        int s = col[i];
        acc += dis[s] * bf2f(xw[(size_t)s * C + c]);
    }
    float r = dd * acc + bias[c];
    if (ACT == 1) r = fmaxf(r, 0.f);
    if constexpr (OBF)
        ((unsigned short*)outp)[(size_t)node * C + c] = f2bf(r);
    else
        ((float*)outp)[(size_t)node * C + c] = r;
}

// ---------------- alpha dot (bf16 features) ----------------
template<int C>
__global__ void alpha_kernel(const unsigned short* __restrict__ xh, const float* __restrict__ a_src,
                             const float* __restrict__ a_dst, float* __restrict__ as_,
                             float* __restrict__ ad_, int n) {
    int wid = threadIdx.x >> 6, lane = threadIdx.x & 63;
    int node = blockIdx.x * 4 + wid;
    if (node >= n) return;
    const unsigned short* xr = xh + (size_t)node * 4 * C;
    float ps[4], pd[4];
    #pragma unroll
    for (int h = 0; h < 4; h++) {
        float v = bf2f(xr[h * C + lane]);
        ps[h] = v * a_src[h * C + lane];
        pd[h] = v * a_dst[h * C + lane];
        if (C == 128) {
            float v2 = bf2f(xr[h * C + lane + 64]);
            ps[h] += v2 * a_src[h * C + lane + 64];
            pd[h] += v2 * a_dst[h * C + lane + 64];
        }
    }
    #pragma unroll
    for (int o = 32; o; o >>= 1) {
        #pragma unroll
        for (int h = 0; h < 4; h++) {
            ps[h] += __shfl_xor(ps[h], o, 64);
            pd[h] += __shfl_xor(pd[h], o, 64);
        }
    }
    if (lane == 0) {
        #pragma unroll
        for (int h = 0; h < 4; h++) {
            as_[(size_t)node * 4 + h] = ps[h];
            ad_[(size_t)node * 4 + h] = pd[h];
        }
    }
}

// ---------------- GAT propagate (bf16 features, per-dst softmax) ----------------
template<int C, bool CONCAT>
__global__ void gat_prop_kernel(const unsigned short* __restrict__ xh, const float* __restrict__ as_,
                                const float* __restrict__ ad_, const int* __restrict__ rowptr,
                                const int* __restrict__ col, const float* __restrict__ bias,
                                void* __restrict__ outp, int n) {
    constexpr int CAP = 256;
    constexpr int NW = C / 64;
    __shared__ float ex[(CAP + 1) * 4];
    __shared__ int scol[CAP + 1];
    __shared__ float wsum[NW][4];
    int node = blockIdx.x;
    int tid = threadIdx.x, lane = tid & 63, wid = tid >> 6;
    int b0 = rowptr[node];
    int cnt = rowptr[node + 1] - b0;
    float4 adv = *reinterpret_cast<const float4*>(&ad_[(size_t)node * 4]);
    float p0 = 0, p1 = 0, p2 = 0, p3 = 0;
    for (int i = tid; i <= cnt; i += C) {
        int s = (i == cnt) ? node : col[b0 + i];
        float4 asv = *reinterpret_cast<const float4*>(&as_[(size_t)s * 4]);
        float e0 = asv.x + adv.x; e0 = e0 > 0.f ? e0 : NEG * e0; float x0 = __expf(e0);
        float e1 = asv.y + adv.y; e1 = e1 > 0.f ? e1 : NEG * e1; float x1 = __expf(e1);
        float e2 = asv.z + adv.z; e2 = e2 > 0.f ? e2 : NEG * e2; float x2 = __expf(e2);
        float e3 = asv.w + adv.w; e3 = e3 > 0.f ? e3 : NEG * e3; float x3 = __expf(e3);
        if (i <= CAP) {
            ex[i * 4 + 0] = x0; ex[i * 4 + 1] = x1;
            ex[i * 4 + 2] = x2; ex[i * 4 + 3] = x3;
            scol[i] = s;
        }
        p0 += x0; p1 += x1; p2 += x2; p3 += x3;
    }
    #pragma unroll
    for (int o = 32; o; o >>= 1) {
        p0 += __shfl_xor(p0, o, 64); p1 += __shfl_xor(p1, o, 64);
        p2 += __shfl_xor(p2, o, 64); p3 += __shfl_xor(p3, o, 64);
    }
    if (lane == 0) { wsum[wid][0] = p0; wsum[wid][1] = p1; wsum[wid][2] = p2; wsum[wid][3] = p3; }
    __syncthreads();
    float d0 = 0, d1 = 0, d2 = 0, d3 = 0;
    #pragma unroll
    for (int w = 0; w < NW; w++) { d0 += wsum[w][0]; d1 += wsum[w][1]; d2 += wsum[w][2]; d3 += wsum[w][3]; }
    constexpr float SC = CONCAT ? 1.f : 0.25f;
    float s0 = SC / d0, s1 = SC / d1, s2 = SC / d2, s3 = SC / d3;

    float acc0 = 0, acc1 = 0, acc2 = 0, acc3 = 0;
    for (int i = 0; i <= cnt; i++) {
        int s; float w0, w1, w2, w3;
        if (i <= CAP) {
            s = scol[i];
            w0 = ex[i * 4 + 0] * s0; w1 = ex[i * 4 + 1] * s1;
            w2 = ex[i * 4 + 2] * s2; w3 = ex[i * 4 + 3] * s3;
        } else {
            s = (i == cnt) ? node : col[b0 + i];
            float4 asv = *reinterpret_cast<const float4*>(&as_[(size_t)s * 4]);
            float e0 = asv.x + adv.x; e0 = e0 > 0.f ? e0 : NEG * e0;
            float e1 = asv.y + adv.y; e1 = e1 > 0.f ? e1 : NEG * e1;
            float e2 = asv.z + adv.z; e2 = e2 > 0.f ? e2 : NEG * e2;
            float e3 = asv.w + adv.w; e3 = e3 > 0.f ? e3 : NEG * e3;
            w0 = __expf(e0) * s0; w1 = __expf(e1) * s1;
            w2 = __expf(e2) * s2; w3 = __expf(e3) * s3;
        }
        const unsigned short* xr = xh + (size_t)s * (4 * C);
        acc0 += w0 * bf2f(xr[0 * C + tid]);
        acc1 += w1 * bf2f(xr[1 * C + tid]);
        acc2 += w2 * bf2f(xr[2 * C + tid]);
        acc3 += w3 * bf2f(xr[3 * C + tid]);
    }
    if (CONCAT) {
        unsigned short* orow = (unsigned short*)outp + (size_t)node * 4 * C;
        float r0 = acc0 + bias[0 * C + tid]; r0 = r0 > 0.f ? r0 : __expf(r0) - 1.f;
        float r1 = acc1 + bias[1 * C + tid]; r1 = r1 > 0.f ? r1 : __expf(r1) - 1.f;
        float r2 = acc2 + bias[2 * C + tid]; r2 = r2 > 0.f ? r2 : __expf(r2) - 1.f;
        float r3 = acc3 + bias[3 * C + tid]; r3 = r3 > 0.f ? r3 : __expf(r3) - 1.f;
        orow[0 * C + tid] = f2bf(r0); orow[1 * C + tid] = f2bf(r1);
        orow[2 * C + tid] = f2bf(r2); orow[3 * C + tid] = f2bf(r3);
    } else {
        ((float*)outp)[(size_t)node * C + tid] = acc0 + acc1 + acc2 + acc3 + bias[tid];
    }
}

// ---------------- LayerNorm both branches -> cat buffer [n, 256] bf16 ----------------
__global__ void ln_kernel(const float* __restrict__ a_gcn, const float* __restrict__ a_gat,
                          const float* __restrict__ gw1, const float* __restrict__ gb1,
                          const float* __restrict__ gw2, const float* __restrict__ gb2,
                          unsigned short* __restrict__ catb, int n) {
    int node = blockIdx.x, tid = threadIdx.x, lane = tid & 63, wid = tid >> 6;
    __shared__ float ws2[2][2];
    #pragma unroll
    for (int half = 0; half < 2; half++) {
        const float* src = half ? a_gat : a_gcn;
        const float* gw = half ? gw2 : gw1;
        const float* gb = half ? gb2 : gb1;
        float v = src[(size_t)node * 128 + tid];
        float s = v, q = v * v;
        #pragma unroll
        for (int o = 32; o; o >>= 1) { s += __shfl_xor(s, o, 64); q += __shfl_xor(q, o, 64); }
        if (lane == 0) { ws2[wid][0] = s; ws2[wid][1] = q; }
        __syncthreads();
        float ts = ws2[0][0] + ws2[1][0], tq = ws2[0][1] + ws2[1][1];
        float mu = ts * (1.f / 128.f);
        float var = tq * (1.f / 128.f) - mu * mu;
        float r = (v - mu) * rsqrtf(var + EPS) * gw[tid] + gb[tid];
        catb[(size_t)node * 256 + half * 128 + tid] = f2bf(r);
        __syncthreads();
    }
}

// ---------------- launch ----------------
extern "C" void kernel_launch(void* const* d_in, const int* in_sizes, int n_in,
                              void* d_out, int out_size, void* d_ws, size_t ws_size,
                              hipStream_t stream) {
    const float* x      = (const float*)d_in[0];
    const int*   ei     = (const int*)d_in[1];
    const float* W_gcn1 = (const float*)d_in[2];
    const float* b_gcn1 = (const float*)d_in[3];
    const float* W_gcn2 = (const float*)d_in[4];
    const float* b_gcn2 = (const float*)d_in[5];
    const float* W_gat1 = (const float*)d_in[6];
    const float* a_src1 = (const float*)d_in[7];
    const float* a_dst1 = (const float*)d_in[8];
    const float* b_gat1 = (const float*)d_in[9];
    const float* W_gat2 = (const float*)d_in[10];
    const float* a_src2 = (const float*)d_in[11];
    const float* a_dst2 = (const float*)d_in[12];
    const float* b_gat2 = (const float*)d_in[13];
    const float* g_gcn  = (const float*)d_in[14];
    const float* bt_gcn = (const float*)d_in[15];
    const float* g_gat  = (const float*)d_in[16];
    const float* bt_gat = (const float*)d_in[17];
    const float* W_fuse = (const float*)d_in[18];
    const float* b_fuse = (const float*)d_in[19];
    float* out = (float*)d_out;

    const int n = in_sizes[0] / 128;
    const int E = in_sizes[1] / 2;

    char* ws = (char*)d_ws;
    size_t off = 0;
    auto alloc = [&](size_t bytes) -> char* {
        char* p = ws + off;
        off += (bytes + 255) & ~(size_t)255;
        return p;
    };
    int*   cnt     = (int*)alloc((size_t)n * 4);
    int*   rowptr  = (int*)alloc((size_t)(n + 1) * 4);
    int*   cursor  = (int*)alloc((size_t)n * 4);
    int*   col     = (int*)alloc((size_t)E * 4);
    float* dis     = (float*)alloc((size_t)n * 4);
    float* as_     = (float*)alloc((size_t)n * 16);
    float* ad_     = (float*)alloc((size_t)n * 16);
    float* gcn_out = (float*)alloc((size_t)n * 128 * 4);
    float* x_gat   = (float*)alloc((size_t)n * 128 * 4);
    unsigned short* xw1b = (unsigned short*)alloc((size_t)n * 64 * 2);
    unsigned short* hb   = (unsigned short*)alloc((size_t)n * 64 * 2);
    unsigned short* xw2b = (unsigned short*)alloc((size_t)n * 128 * 2);
    unsigned short* xh1b = (unsigned short*)alloc((size_t)n * 256 * 2);
    unsigned short* g1b  = (unsigned short*)alloc((size_t)n * 256 * 2);
    unsigned short* xh2b = (unsigned short*)alloc((size_t)n * 512 * 2);
    unsigned short* catb = xh2b;  // xh2 dead before LN writes catb

    // CSR build
    hipMemsetAsync(cnt, 0, (size_t)n * 4, stream);
    count_kernel<<<(E + 255) / 256, 256, 0, stream>>>(ei, cnt, E);
    scan_kernel<<<1, 1024, 0, stream>>>(cnt, rowptr, n);
    prep_kernel<<<(n + 255) / 256, 256, 0, stream>>>(rowptr, cnt, cursor, dis, n);
    fill_kernel<<<(E + 255) / 256, 256, 0, stream>>>(ei, cursor, col, E);

    int gm = (n + 127) / 128;

    // GCN branch
    mfma_gemm<128, 64, false, true><<<dim3(gm, 1), 256, 0, stream>>>(x, W_gcn1, nullptr, xw1b, n);
    gcn_prop_kernel<64, 1, true><<<n, 64, 0, stream>>>(xw1b, dis, rowptr, col, b_gcn1, hb, n);
    mfma_gemm<64, 128, true, true><<<dim3(gm, 2), 256, 0, stream>>>(hb, W_gcn2, nullptr, xw2b, n);
    gcn_prop_kernel<128, 0, false><<<n, 128, 0, stream>>>(xw2b, dis, rowptr, col, b_gcn2, gcn_out, n);

    // GAT branch
    mfma_gemm<128, 256, false, true><<<dim3(gm, 4), 256, 0, stream>>>(x, W_gat1, nullptr, xh1b, n);
    alpha_kernel<64><<<(n + 3) / 4, 256, 0, stream>>>(xh1b, a_src1, a_dst1, as_, ad_, n);
    gat_prop_kernel<64, true><<<n, 64, 0, stream>>>(xh1b, as_, ad_, rowptr, col, b_gat1, g1b, n);
    mfma_gemm<256, 512, true, true><<<dim3(gm, 8), 256, 0, stream>>>(g1b, W_gat2, nullptr, xh2b, n);
    alpha_kernel<128><<<(n + 3) / 4, 256, 0, stream>>>(xh2b, a_src2, a_dst2, as_, ad_, n);
    gat_prop_kernel<128, false><<<n, 128, 0, stream>>>(xh2b, as_, ad_, rowptr, col, b_gat2, x_gat, n);

    // LN + concat + fuse
    ln_kernel<<<n, 128, 0, stream>>>(gcn_out, x_gat, g_gcn, bt_gcn, g_gat, bt_gat, catb, n);
    mfma_gemm<256, 128, true, false><<<dim3(gm, 2), 256, 0, stream>>>(catb, W_fuse, b_fuse, out, n);
}

// Round 4
// 463.779 us; speedup vs baseline: 4.0347x; 1.1562x over previous
//
#include <hip/hip_runtime.h>
#include <cmath>

static constexpr float EPS = 1e-5f;
static constexpr float NEG = 0.2f;

typedef __attribute__((ext_vector_type(8))) short short8v;
typedef __attribute__((ext_vector_type(4))) short short4v;
typedef __attribute__((ext_vector_type(4))) float f32x4;

__device__ inline unsigned short f2bf(float f) {
    union { float f; unsigned u; } v; v.f = f;
    unsigned r = v.u + 0x7FFF + ((v.u >> 16) & 1);   // RNE
    return (unsigned short)(r >> 16);
}
__device__ inline float bf2f(unsigned short u) {
    union { unsigned u; float f; } v; v.u = (unsigned)u << 16; return v.f;
}

// ---------------- CSR build ----------------
__global__ void count_kernel(const int* __restrict__ ei, int* __restrict__ cnt, int E) {
    int e = blockIdx.x * 256 + threadIdx.x;
    if (e < E) atomicAdd(&cnt[ei[E + e]], 1);
}

__global__ void scan_kernel(const int* __restrict__ cnt, int* __restrict__ rowptr, int n) {
    __shared__ int part[1024];
    int tid = threadIdx.x;
    int chunk = (n + 1023) >> 10;
    int s0 = tid * chunk;
    int s1 = s0 + chunk; if (s1 > n) s1 = n;
    int s = 0;
    for (int i = s0; i < s1; i++) s += cnt[i];
    part[tid] = s;
    __syncthreads();
    for (int off = 1; off < 1024; off <<= 1) {
        int v = (tid >= off) ? part[tid - off] : 0;
        __syncthreads();
        part[tid] += v;
        __syncthreads();
    }
    int run = (tid == 0) ? 0 : part[tid - 1];
    for (int i = s0; i < s1; i++) { rowptr[i] = run; run += cnt[i]; }
    if (tid == 1023) rowptr[n] = part[1023];
}

__global__ void prep_kernel(const int* __restrict__ rowptr, const int* __restrict__ cnt,
                            int* __restrict__ cursor, float* __restrict__ dis, int n) {
    int i = blockIdx.x * 256 + threadIdx.x;
    if (i < n) {
        cursor[i] = rowptr[i];
        dis[i] = rsqrtf((float)(cnt[i] + 1));
    }
}

__global__ void fill_kernel(const int* __restrict__ ei, int* __restrict__ cursor,
                            int* __restrict__ col, int E) {
    int e = blockIdx.x * 256 + threadIdx.x;
    if (e < E) {
        int d = ei[E + e];
        int pos = atomicAdd(&cursor[d], 1);
        col[pos] = ei[e];
    }
}

// ---------------- converts ----------------
__global__ void convert_x_kernel(const float* __restrict__ x, unsigned short* __restrict__ xb, int total4) {
    int i = blockIdx.x * 256 + threadIdx.x;
    if (i < total4) {
        float4 v = *reinterpret_cast<const float4*>(&x[(size_t)i * 4]);
        unsigned long long pk = (unsigned long long)f2bf(v.x)
                              | ((unsigned long long)f2bf(v.y) << 16)
                              | ((unsigned long long)f2bf(v.z) << 32)
                              | ((unsigned long long)f2bf(v.w) << 48);
        *reinterpret_cast<unsigned long long*>(&xb[(size_t)i * 4]) = pk;
    }
}

// transpose+convert all 5 weight matrices: T[c*K+k] = bf16(W[k*C+c])
__global__ void convert_weights_kernel(const float* W1, const float* W2, const float* W3,
                                       const float* W4, const float* W5,
                                       unsigned short* T1, unsigned short* T2, unsigned short* T3,
                                       unsigned short* T4, unsigned short* T5) {
    int idx = blockIdx.x * 256 + threadIdx.x;
    const float* S; unsigned short* D; int K, C, off;
    if      (idx <   8192) { S = W1; D = T1; K = 128; C =  64; off = 0; }
    else if (idx <  16384) { S = W2; D = T2; K =  64; C = 128; off = 8192; }
    else if (idx <  49152) { S = W3; D = T3; K = 128; C = 256; off = 16384; }
    else if (idx < 180224) { S = W4; D = T4; K = 256; C = 512; off = 49152; }
    else if (idx < 212992) { S = W5; D = T5; K = 256; C = 128; off = 180224; }
    else return;
    int j = idx - off;
    int c = j / K, k = j % K;
    D[j] = f2bf(S[(size_t)k * C + c]);
}

// ---------------- MFMA GEMM: out[M,C] = A[M,K](bf16) @ W[K,C] (+bias) ----------------
// WT: bf16 transposed weights [C][K]. fp32 accumulate. out fp32 or bf16.
template<int K, int C, bool OBF>
__global__ __launch_bounds__(256) void mfma_gemm(const unsigned short* __restrict__ A,
                                                 const unsigned short* __restrict__ WT,
                                                 const float* __restrict__ bias,
                                                 void* __restrict__ outp, int M) {
    constexpr int BM = 128, BN = 64, BK = 64;
    __shared__ unsigned short As[BM * BK];
    __shared__ unsigned short Ws[BN * BK];
    int tid = threadIdx.x;
    int wid = tid >> 6, lane = tid & 63;
    int m0 = blockIdx.x * BM;
    int n0 = blockIdx.y * BN;

    f32x4 acc[2][4] = {};

    for (int k0 = 0; k0 < K; k0 += BK) {
        for (int i = tid; i < BM * (BK / 8); i += 256) {
            int row = i >> 3;
            int kk = (i & 7) * 8;
            int gr = m0 + row;
            short8v v = short8v{0, 0, 0, 0, 0, 0, 0, 0};
            if (gr < M) v = *reinterpret_cast<const short8v*>(&A[(size_t)gr * K + k0 + kk]);
            int byte = (kk * 2) ^ ((row & 7) << 4);
            *reinterpret_cast<short8v*>((char*)As + row * (BK * 2) + byte) = v;
        }
        for (int i = tid; i < BN * (BK / 8); i += 256) {
            int nrow = i >> 3;
            int kk = (i & 7) * 8;
            short8v v = *reinterpret_cast<const short8v*>(&WT[(size_t)(n0 + nrow) * K + k0 + kk]);
            int byte = (kk * 2) ^ ((nrow & 7) << 4);
            *reinterpret_cast<short8v*>((char*)Ws + nrow * (BK * 2) + byte) = v;
        }
        __syncthreads();
        #pragma unroll
        for (int kc = 0; kc < BK; kc += 32) {
            short8v afr[2], bfr[4];
            int kk = kc + (lane >> 4) * 8;
            #pragma unroll
            for (int mf = 0; mf < 2; mf++) {
                int row = wid * 32 + mf * 16 + (lane & 15);
                int byte = (kk * 2) ^ ((row & 7) << 4);
                afr[mf] = *reinterpret_cast<const short8v*>((char*)As + row * (BK * 2) + byte);
            }
            #pragma unroll
            for (int nf = 0; nf < 4; nf++) {
                int nrow = nf * 16 + (lane & 15);
                int byte = (kk * 2) ^ ((nrow & 7) << 4);
                bfr[nf] = *reinterpret_cast<const short8v*>((char*)Ws + nrow * (BK * 2) + byte);
            }
            #pragma unroll
            for (int mf = 0; mf < 2; mf++)
                #pragma unroll
                for (int nf = 0; nf < 4; nf++)
                    acc[mf][nf] = __builtin_amdgcn_mfma_f32_16x16x32_bf16(
                        afr[mf], bfr[nf], acc[mf][nf], 0, 0, 0);
        }
        __syncthreads();
    }
    #pragma unroll
    for (int mf = 0; mf < 2; mf++) {
        #pragma unroll
        for (int nf = 0; nf < 4; nf++) {
            #pragma unroll
            for (int r = 0; r < 4; r++) {
                int row = m0 + wid * 32 + mf * 16 + (lane >> 4) * 4 + r;
                int colg = n0 + nf * 16 + (lane & 15);
                if (row < M) {
                    float v = acc[mf][nf][r];
                    if (bias) v += bias[colg];
                    if constexpr (OBF)
                        ((unsigned short*)outp)[(size_t)row * C + colg] = f2bf(v);
                    else
                        ((float*)outp)[(size_t)row * C + colg] = v;
                }
            }
        }
    }
}

// ---------------- GCN layer1 prop: relu, bf16 out. wave per node, 1 ch/lane ----------------
__global__ __launch_bounds__(256) void gcn_prop1_kernel(const unsigned short* __restrict__ xw,
                                                        const float* __restrict__ dis,
                                                        const int* __restrict__ rowptr,
                                                        const int* __restrict__ col,
                                                        const float* __restrict__ bias,
                                                        unsigned short* __restrict__ outp, int n) {
    int wid = threadIdx.x >> 6, lane = threadIdx.x & 63;
    int node = blockIdx.x * 4 + wid;
    if (node >= n) return;
    float dd = dis[node];
    float acc = dd * bf2f(xw[(size_t)node * 64 + lane]);
    int b0 = rowptr[node], b1 = rowptr[node + 1];
    for (int i = b0; i < b1; i++) {
        int s = col[i];
        acc += dis[s] * bf2f(xw[(size_t)s * 64 + lane]);
    }
    float r = dd * acc + bias[lane];
    r = fmaxf(r, 0.f);
    outp[(size_t)node * 64 + lane] = f2bf(r);
}

// ---------------- GCN layer2 prop + LayerNorm -> catb[:, :128]. wave per node, 2 ch/lane ----------------
__global__ __launch_bounds__(256) void gcn_prop2_ln_kernel(const unsigned short* __restrict__ xw,
                                                           const float* __restrict__ dis,
                                                           const int* __restrict__ rowptr,
                                                           const int* __restrict__ col,
                                                           const float* __restrict__ bias,
                                                           const float* __restrict__ gw,
                                                           const float* __restrict__ gb,
                                                           unsigned short* __restrict__ catb, int n) {
    int wid = threadIdx.x >> 6, lane = threadIdx.x & 63;
    int node = blockIdx.x * 4 + wid;
    if (node >= n) return;
    float dd = dis[node];
    unsigned vs = *reinterpret_cast<const unsigned*>(&xw[(size_t)node * 128 + lane * 2]);
    float a0 = dd * bf2f((unsigned short)(vs & 0xFFFF));
    float a1 = dd * bf2f((unsigned short)(vs >> 16));
    int b0 = rowptr[node], b1 = rowptr[node + 1];
    for (int i = b0; i < b1; i++) {
        int s = col[i];
        float ds = dis[s];
        unsigned v = *reinterpret_cast<const unsigned*>(&xw[(size_t)s * 128 + lane * 2]);
        a0 += ds * bf2f((unsigned short)(v & 0xFFFF));
        a1 += ds * bf2f((unsigned short)(v >> 16));
    }
    float r0 = dd * a0 + bias[lane * 2];
    float r1 = dd * a1 + bias[lane * 2 + 1];
    // LN over 128 channels (64 lanes x 2)
    float sm = r0 + r1, sq = r0 * r0 + r1 * r1;
    #pragma unroll
    for (int o = 1; o < 64; o <<= 1) { sm += __shfl_xor(sm, o, 64); sq += __shfl_xor(sq, o, 64); }
    float mu = sm * (1.f / 128.f);
    float var = sq * (1.f / 128.f) - mu * mu;
    float rs = rsqrtf(var + EPS);
    float o0 = (r0 - mu) * rs * gw[lane * 2] + gb[lane * 2];
    float o1 = (r1 - mu) * rs * gw[lane * 2 + 1] + gb[lane * 2 + 1];
    unsigned pk = (unsigned)f2bf(o0) | ((unsigned)f2bf(o1) << 16);
    *reinterpret_cast<unsigned*>(&catb[(size_t)node * 256 + lane * 2]) = pk;
}

// ---------------- alpha dots. wave per node ----------------
// L1: xh [n,256] (4 heads x 64), a [4][64]. L2: xh [n,512] (4 heads x 128), a [4][128].
template<int HC>  // per-head channels: 64 or 128
__global__ __launch_bounds__(256) void alpha_kernel(const unsigned short* __restrict__ xh,
                                                    const float* __restrict__ a_src,
                                                    const float* __restrict__ a_dst,
                                                    float* __restrict__ as_, float* __restrict__ ad_, int n) {
    constexpr int PL = HC / 16;   // elems per lane: 4 or 8
    int wid = threadIdx.x >> 6, lane = threadIdx.x & 63;
    int node = blockIdx.x * 4 + wid;
    if (node >= n) return;
    int head = lane >> 4, cb = (lane & 15) * PL;
    const unsigned short* xr = xh + (size_t)node * (4 * HC) + lane * PL;
    float ps = 0.f, pd = 0.f;
    #pragma unroll
    for (int j = 0; j < PL; j++) {
        float v = bf2f(xr[j]);
        ps += v * a_src[head * HC + cb + j];
        pd += v * a_dst[head * HC + cb + j];
    }
    #pragma unroll
    for (int o = 1; o < 16; o <<= 1) { ps += __shfl_xor(ps, o, 64); pd += __shfl_xor(pd, o, 64); }
    if ((lane & 15) == 0) {
        as_[(size_t)node * 4 + head] = ps;
        ad_[(size_t)node * 4 + head] = pd;
    }
}

// ---------------- GAT layer1 prop: concat, ELU, bf16 out [n,256]. wave per node ----------------
__global__ __launch_bounds__(256) void gat_prop1_kernel(const unsigned short* __restrict__ xh,
                                                        const float* __restrict__ as_,
                                                        const float* __restrict__ ad_,
                                                        const int* __restrict__ rowptr,
                                                        const int* __restrict__ col,
                                                        const float* __restrict__ bias,
                                                        unsigned short* __restrict__ outp, int n) {
    constexpr int CAP = 96;
    __shared__ float ex[4][CAP][4];
    __shared__ int scol[4][CAP];
    int wid = threadIdx.x >> 6, lane = threadIdx.x & 63;
    int node = blockIdx.x * 4 + wid;
    if (node >= n) return;
    int b0 = rowptr[node];
    int cnt = rowptr[node + 1] - b0;
    float4 adv = *reinterpret_cast<const float4*>(&ad_[(size_t)node * 4]);
    float p0 = 0, p1 = 0, p2 = 0, p3 = 0;
    for (int i = lane; i <= cnt; i += 64) {
        int s = (i == cnt) ? node : col[b0 + i];
        float4 asv = *reinterpret_cast<const float4*>(&as_[(size_t)s * 4]);
        float e0 = asv.x + adv.x; e0 = e0 > 0.f ? e0 : NEG * e0; float x0 = __expf(e0);
        float e1 = asv.y + adv.y; e1 = e1 > 0.f ? e1 : NEG * e1; float x1 = __expf(e1);
        float e2 = asv.z + adv.z; e2 = e2 > 0.f ? e2 : NEG * e2; float x2 = __expf(e2);
        float e3 = asv.w + adv.w; e3 = e3 > 0.f ? e3 : NEG * e3; float x3 = __expf(e3);
        if (i < CAP) {
            ex[wid][i][0] = x0; ex[wid][i][1] = x1; ex[wid][i][2] = x2; ex[wid][i][3] = x3;
            scol[wid][i] = s;
        }
        p0 += x0; p1 += x1; p2 += x2; p3 += x3;
    }
    #pragma unroll
    for (int o = 1; o < 64; o <<= 1) {
        p0 += __shfl_xor(p0, o, 64); p1 += __shfl_xor(p1, o, 64);
        p2 += __shfl_xor(p2, o, 64); p3 += __shfl_xor(p3, o, 64);
    }
    __builtin_amdgcn_wave_barrier();
    int head = lane >> 4;
    float wsel = head == 0 ? 1.f / p0 : head == 1 ? 1.f / p1 : head == 2 ? 1.f / p2 : 1.f / p3;
    int coff = lane * 4;   // position within 256-wide row (head*64 + inner)
    float fa0 = 0, fa1 = 0, fa2 = 0, fa3 = 0;
    for (int i = 0; i <= cnt; i++) {
        int s; float we;
        if (i < CAP) {
            s = scol[wid][i];
            we = ex[wid][i][head] * wsel;
        } else {
            s = (i == cnt) ? node : col[b0 + i];
            float4 asv = *reinterpret_cast<const float4*>(&as_[(size_t)s * 4]);
            float eh = head == 0 ? asv.x + adv.x : head == 1 ? asv.y + adv.y
                     : head == 2 ? asv.z + adv.z : asv.w + adv.w;
            eh = eh > 0.f ? eh : NEG * eh;
            we = __expf(eh) * wsel;
        }
        short4v v = *reinterpret_cast<const short4v*>(&xh[(size_t)s * 256 + coff]);
        fa0 += we * bf2f((unsigned short)v[0]);
        fa1 += we * bf2f((unsigned short)v[1]);
        fa2 += we * bf2f((unsigned short)v[2]);
        fa3 += we * bf2f((unsigned short)v[3]);
    }
    float r0 = fa0 + bias[coff];     r0 = r0 > 0.f ? r0 : __expf(r0) - 1.f;
    float r1 = fa1 + bias[coff + 1]; r1 = r1 > 0.f ? r1 : __expf(r1) - 1.f;
    float r2 = fa2 + bias[coff + 2]; r2 = r2 > 0.f ? r2 : __expf(r2) - 1.f;
    float r3 = fa3 + bias[coff + 3]; r3 = r3 > 0.f ? r3 : __expf(r3) - 1.f;
    short4v o4;
    o4[0] = (short)f2bf(r0); o4[1] = (short)f2bf(r1);
    o4[2] = (short)f2bf(r2); o4[3] = (short)f2bf(r3);
    *reinterpret_cast<short4v*>(&outp[(size_t)node * 256 + coff]) = o4;
}

// ---------------- GAT layer2 prop: head-mean + bias + LayerNorm -> catb[:, 128:]. wave per node ----------------
__global__ __launch_bounds__(256) void gat_prop2_ln_kernel(const unsigned short* __restrict__ xh,
                                                           const float* __restrict__ as_,
                                                           const float* __restrict__ ad_,
                                                           const int* __restrict__ rowptr,
                                                           const int* __restrict__ col,
                                                           const float* __restrict__ bias,
                                                           const float* __restrict__ gw,
                                                           const float* __restrict__ gb,
                                                           unsigned short* __restrict__ catb, int n) {
    constexpr int CAP = 96;
    __shared__ float ex[4][CAP][4];
    __shared__ int scol[4][CAP];
    int wid = threadIdx.x >> 6, lane = threadIdx.x & 63;
    int node = blockIdx.x * 4 + wid;
    if (node >= n) return;
    int b0 = rowptr[node];
    int cnt = rowptr[node + 1] - b0;
    float4 adv = *reinterpret_cast<const float4*>(&ad_[(size_t)node * 4]);
    float p0 = 0, p1 = 0, p2 = 0, p3 = 0;
    for (int i = lane; i <= cnt; i += 64) {
        int s = (i == cnt) ? node : col[b0 + i];
        float4 asv = *reinterpret_cast<const float4*>(&as_[(size_t)s * 4]);
        float e0 = asv.x + adv.x; e0 = e0 > 0.f ? e0 : NEG * e0; float x0 = __expf(e0);
        float e1 = asv.y + adv.y; e1 = e1 > 0.f ? e1 : NEG * e1; float x1 = __expf(e1);
        float e2 = asv.z + adv.z; e2 = e2 > 0.f ? e2 : NEG * e2; float x2 = __expf(e2);
        float e3 = asv.w + adv.w; e3 = e3 > 0.f ? e3 : NEG * e3; float x3 = __expf(e3);
        if (i < CAP) {
            ex[wid][i][0] = x0; ex[wid][i][1] = x1; ex[wid][i][2] = x2; ex[wid][i][3] = x3;
            scol[wid][i] = s;
        }
        p0 += x0; p1 += x1; p2 += x2; p3 += x3;
    }
    #pragma unroll
    for (int o = 1; o < 64; o <<= 1) {
        p0 += __shfl_xor(p0, o, 64); p1 += __shfl_xor(p1, o, 64);
        p2 += __shfl_xor(p2, o, 64); p3 += __shfl_xor(p3, o, 64);
    }
    __builtin_amdgcn_wave_barrier();
    int head = lane >> 4;
    float wsel = head == 0 ? 0.25f / p0 : head == 1 ? 0.25f / p1 : head == 2 ? 0.25f / p2 : 0.25f / p3;
    int cw = (lane & 15) * 8;  // within-head channel base
    float facc[8] = {0, 0, 0, 0, 0, 0, 0, 0};
    for (int i = 0; i <= cnt; i++) {
        int s; float we;
        if (i < CAP) {
            s = scol[wid][i];
            we = ex[wid][i][head] * wsel;
        } else {
            s = (i == cnt) ? node : col[b0 + i];
            float4 asv = *reinterpret_cast<const float4*>(&as_[(size_t)s * 4]);
            float eh = head == 0 ? asv.x + adv.x : head == 1 ? asv.y + adv.y
                     : head == 2 ? asv.z + adv.z : asv.w + adv.w;
            eh = eh > 0.f ? eh : NEG * eh;
            we = __expf(eh) * wsel;
        }
        short8v v = *reinterpret_cast<const short8v*>(&xh[(size_t)s * 512 + lane * 8]);
        #pragma unroll
        for (int j = 0; j < 8; j++) facc[j] += we * bf2f((unsigned short)v[j]);
    }
    // sum over heads (lanes 16 apart hold same channels, different heads)
    #pragma unroll
    for (int j = 0; j < 8; j++) {
        facc[j] += __shfl_xor(facc[j], 16, 64);
        facc[j] += __shfl_xor(facc[j], 32, 64);
        facc[j] += bias[cw + j];
    }
    // LN over 128 channels (16-lane groups hold full row; groups are replicas)
    float sm = 0, sq = 0;
    #pragma unroll
    for (int j = 0; j < 8; j++) { sm += facc[j]; sq += facc[j] * facc[j]; }
    #pragma unroll
    for (int o = 1; o < 16; o <<= 1) { sm += __shfl_xor(sm, o, 64); sq += __shfl_xor(sq, o, 64); }
    float mu = sm * (1.f / 128.f);
    float var = sq * (1.f / 128.f) - mu * mu;
    float rs = rsqrtf(var + EPS);
    if (lane < 16) {
        short8v o8;
        #pragma unroll
        for (int j = 0; j < 8; j++)
            o8[j] = (short)f2bf((facc[j] - mu) * rs * gw[cw + j] + gb[cw + j]);
        *reinterpret_cast<short8v*>(&catb[(size_t)node * 256 + 128 + cw]) = o8;
    }
}

// ---------------- launch ----------------
extern "C" void kernel_launch(void* const* d_in, const int* in_sizes, int n_in,
                              void* d_out, int out_size, void* d_ws, size_t ws_size,
                              hipStream_t stream) {
    const float* x      = (const float*)d_in[0];
    const int*   ei     = (const int*)d_in[1];
    const float* W_gcn1 = (const float*)d_in[2];
    const float* b_gcn1 = (const float*)d_in[3];
    const float* W_gcn2 = (const float*)d_in[4];
    const float* b_gcn2 = (const float*)d_in[5];
    const float* W_gat1 = (const float*)d_in[6];
    const float* a_src1 = (const float*)d_in[7];
    const float* a_dst1 = (const float*)d_in[8];
    const float* b_gat1 = (const float*)d_in[9];
    const float* W_gat2 = (const float*)d_in[10];
    const float* a_src2 = (const float*)d_in[11];
    const float* a_dst2 = (const float*)d_in[12];
    const float* b_gat2 = (const float*)d_in[13];
    const float* g_gcn  = (const float*)d_in[14];
    const float* bt_gcn = (const float*)d_in[15];
    const float* g_gat  = (const float*)d_in[16];
    const float* bt_gat = (const float*)d_in[17];
    const float* W_fuse = (const float*)d_in[18];
    const float* b_fuse = (const float*)d_in[19];
    float* out = (float*)d_out;

    const int n = in_sizes[0] / 128;
    const int E = in_sizes[1] / 2;

    char* ws = (char*)d_ws;
    size_t off = 0;
    auto alloc = [&](size_t bytes) -> char* {
        char* p = ws + off;
        off += (bytes + 255) & ~(size_t)255;
        return p;
    };
    int*   cnt     = (int*)alloc((size_t)n * 4);
    int*   rowptr  = (int*)alloc((size_t)(n + 1) * 4);
    int*   cursor  = (int*)alloc((size_t)n * 4);
    int*   col     = (int*)alloc((size_t)E * 4);
    float* dis     = (float*)alloc((size_t)n * 4);
    float* as_     = (float*)alloc((size_t)n * 16);
    float* ad_     = (float*)alloc((size_t)n * 16);
    unsigned short* xb   = (unsigned short*)alloc((size_t)n * 128 * 2);
    unsigned short* WT1  = (unsigned short*)alloc(8192 * 2);
    unsigned short* WT2  = (unsigned short*)alloc(8192 * 2);
    unsigned short* WT3  = (unsigned short*)alloc(32768 * 2);
    unsigned short* WT4  = (unsigned short*)alloc(131072 * 2);
    unsigned short* WT5  = (unsigned short*)alloc(32768 * 2);
    unsigned short* xw1b = (unsigned short*)alloc((size_t)n * 64 * 2);
    unsigned short* hb   = (unsigned short*)alloc((size_t)n * 64 * 2);
    unsigned short* xw2b = (unsigned short*)alloc((size_t)n * 128 * 2);
    unsigned short* xh1b = (unsigned short*)alloc((size_t)n * 256 * 2);
    unsigned short* g1b  = (unsigned short*)alloc((size_t)n * 256 * 2);
    unsigned short* xh2b = (unsigned short*)alloc((size_t)n * 512 * 2);
    unsigned short* catb = (unsigned short*)alloc((size_t)n * 256 * 2);

    // CSR build + converts
    hipMemsetAsync(cnt, 0, (size_t)n * 4, stream);
    count_kernel<<<(E + 255) / 256, 256, 0, stream>>>(ei, cnt, E);
    scan_kernel<<<1, 1024, 0, stream>>>(cnt, rowptr, n);
    prep_kernel<<<(n + 255) / 256, 256, 0, stream>>>(rowptr, cnt, cursor, dis, n);
    fill_kernel<<<(E + 255) / 256, 256, 0, stream>>>(ei, cursor, col, E);
    convert_x_kernel<<<(n * 32 + 255) / 256, 256, 0, stream>>>(x, xb, n * 32);
    convert_weights_kernel<<<(212992 + 255) / 256, 256, 0, stream>>>(
        W_gcn1, W_gcn2, W_gat1, W_gat2, W_fuse, WT1, WT2, WT3, WT4, WT5);

    int gm = (n + 127) / 128;
    int gn4 = (n + 3) / 4;

    // GCN branch
    mfma_gemm<128, 64, true><<<dim3(gm, 1), 256, 0, stream>>>(xb, WT1, nullptr, xw1b, n);
    gcn_prop1_kernel<<<gn4, 256, 0, stream>>>(xw1b, dis, rowptr, col, b_gcn1, hb, n);
    mfma_gemm<64, 128, true><<<dim3(gm, 2), 256, 0, stream>>>(hb, WT2, nullptr, xw2b, n);
    gcn_prop2_ln_kernel<<<gn4, 256, 0, stream>>>(xw2b, dis, rowptr, col, b_gcn2, g_gcn, bt_gcn, catb, n);

    // GAT branch
    mfma_gemm<128, 256, true><<<dim3(gm, 4), 256, 0, stream>>>(xb, WT3, nullptr, xh1b, n);
    alpha_kernel<64><<<gn4, 256, 0, stream>>>(xh1b, a_src1, a_dst1, as_, ad_, n);
    gat_prop1_kernel<<<gn4, 256, 0, stream>>>(xh1b, as_, ad_, rowptr, col, b_gat1, g1b, n);
    mfma_gemm<256, 512, true><<<dim3(gm, 8), 256, 0, stream>>>(g1b, WT4, nullptr, xh2b, n);
    alpha_kernel<128><<<gn4, 256, 0, stream>>>(xh2b, a_src2, a_dst2, as_, ad_, n);
    gat_prop2_ln_kernel<<<gn4, 256, 0, stream>>>(xh2b, as_, ad_, rowptr, col, b_gat2, g_gat, bt_gat, catb, n);

    // fuse
    mfma_gemm<256, 128, false><<<dim3(gm, 2), 256, 0, stream>>>(catb, WT5, b_fuse, out, n);
}

// Round 5
// 394.335 us; speedup vs baseline: 4.7452x; 1.1761x over previous
//
#include <hip/hip_runtime.h>
#include <cmath>

static constexpr float EPS = 1e-5f;
static constexpr float NEG = 0.2f;

typedef __attribute__((ext_vector_type(8))) short short8v;
typedef __attribute__((ext_vector_type(4))) short short4v;
typedef __attribute__((ext_vector_type(4))) float f32x4;

__device__ inline unsigned short f2bf(float f) {
    union { float f; unsigned u; } v; v.f = f;
    unsigned r = v.u + 0x7FFF + ((v.u >> 16) & 1);   // RNE
    return (unsigned short)(r >> 16);
}
__device__ inline float bf2f(unsigned short u) {
    union { unsigned u; float f; } v; v.u = (unsigned)u << 16; return v.f;
}

// ---------------- CSR build ----------------
__global__ void count_kernel(const int* __restrict__ ei, int* __restrict__ cnt, int E) {
    int e = blockIdx.x * 256 + threadIdx.x;
    if (e < E) atomicAdd(&cnt[ei[E + e]], 1);
}

// phase 1: per-block (1024 counts) sums
__global__ __launch_bounds__(256) void partial_kernel(const int* __restrict__ cnt,
                                                      int* __restrict__ partials, int n) {
    int tid = threadIdx.x, lane = tid & 63, wid = tid >> 6;
    int base = blockIdx.x * 1024 + tid * 4;
    int s = 0;
    if (base + 3 < n) {
        int4 v = *reinterpret_cast<const int4*>(&cnt[base]);
        s = v.x + v.y + v.z + v.w;
    } else {
        for (int j = 0; j < 4; j++) if (base + j < n) s += cnt[base + j];
    }
    #pragma unroll
    for (int o = 32; o; o >>= 1) s += __shfl_xor(s, o, 64);
    __shared__ int ws[4];
    if (lane == 0) ws[wid] = s;
    __syncthreads();
    if (tid == 0) partials[blockIdx.x] = ws[0] + ws[1] + ws[2] + ws[3];
}

// phase 2: exclusive scan of <=64 partials (one wave)
__global__ void scanp_kernel(int* __restrict__ partials, int nb) {
    int lane = threadIdx.x;
    int v = (lane < nb) ? partials[lane] : 0;
    int s = v;
    #pragma unroll
    for (int o = 1; o < 64; o <<= 1) {
        int t = __shfl_up(s, o, 64);
        if (lane >= o) s += t;
    }
    if (lane < nb) partials[lane] = s - v;   // exclusive
}

// phase 3: in-block exclusive scan + write rowptr/cursor/dis
__global__ __launch_bounds__(256) void scan2_kernel(const int* __restrict__ cnt,
                                                    const int* __restrict__ partials,
                                                    int* __restrict__ rowptr,
                                                    int* __restrict__ cursor,
                                                    float* __restrict__ dis, int n, int E) {
    int tid = threadIdx.x, lane = tid & 63, wid = tid >> 6;
    int base = blockIdx.x * 1024 + tid * 4;
    int v[4]; int s = 0;
    #pragma unroll
    for (int j = 0; j < 4; j++) { v[j] = (base + j < n) ? cnt[base + j] : 0; s += v[j]; }
    int ts = s;
    #pragma unroll
    for (int o = 1; o < 64; o <<= 1) {
        int t = __shfl_up(ts, o, 64);
        if (lane >= o) ts += t;
    }
    __shared__ int wsum[4];
    if (lane == 63) wsum[wid] = ts;
    __syncthreads();
    int woff = 0;
    for (int w = 0; w < wid; w++) woff += wsum[w];
    int excl = ts - s + woff + partials[blockIdx.x];
    #pragma unroll
    for (int j = 0; j < 4; j++) {
        int idx = base + j;
        if (idx < n) {
            rowptr[idx] = excl;
            cursor[idx] = excl;
            dis[idx] = rsqrtf((float)(v[j] + 1));
            excl += v[j];
        }
    }
    if (blockIdx.x == 0 && tid == 0) rowptr[n] = E;
}

__global__ void fill_kernel(const int* __restrict__ ei, int* __restrict__ cursor,
                            int* __restrict__ col, int E) {
    int e = blockIdx.x * 256 + threadIdx.x;
    if (e < E) {
        int d = ei[E + e];
        int pos = atomicAdd(&cursor[d], 1);
        col[pos] = ei[e];
    }
}

// ---------------- converts ----------------
__global__ void convert_x_kernel(const float* __restrict__ x, unsigned short* __restrict__ xb, int total4) {
    int i = blockIdx.x * 256 + threadIdx.x;
    if (i < total4) {
        float4 v = *reinterpret_cast<const float4*>(&x[(size_t)i * 4]);
        unsigned long long pk = (unsigned long long)f2bf(v.x)
                              | ((unsigned long long)f2bf(v.y) << 16)
                              | ((unsigned long long)f2bf(v.z) << 32)
                              | ((unsigned long long)f2bf(v.w) << 48);
        *reinterpret_cast<unsigned long long*>(&xb[(size_t)i * 4]) = pk;
    }
}

// transpose+convert all 5 weight matrices: T[c*K+k] = bf16(W[k*C+c])
__global__ void convert_weights_kernel(const float* W1, const float* W2, const float* W3,
                                       const float* W4, const float* W5,
                                       unsigned short* T1, unsigned short* T2, unsigned short* T3,
                                       unsigned short* T4, unsigned short* T5) {
    int idx = blockIdx.x * 256 + threadIdx.x;
    const float* S; unsigned short* D; int K, C, off;
    if      (idx <   8192) { S = W1; D = T1; K = 128; C =  64; off = 0; }
    else if (idx <  16384) { S = W2; D = T2; K =  64; C = 128; off = 8192; }
    else if (idx <  49152) { S = W3; D = T3; K = 128; C = 256; off = 16384; }
    else if (idx < 180224) { S = W4; D = T4; K = 256; C = 512; off = 49152; }
    else if (idx < 212992) { S = W5; D = T5; K = 256; C = 128; off = 180224; }
    else return;
    int j = idx - off;
    int c = j / K, k = j % K;
    D[j] = f2bf(S[(size_t)k * C + c]);
}

// ---------------- MFMA GEMM: out[M,C] = A[M,K](bf16) @ W[K,C] (+bias) ----------------
template<int K, int C, bool OBF>
__global__ __launch_bounds__(256) void mfma_gemm(const unsigned short* __restrict__ A,
                                                 const unsigned short* __restrict__ WT,
                                                 const float* __restrict__ bias,
                                                 void* __restrict__ outp, int M) {
    constexpr int BM = 128, BN = 64, BK = 64;
    __shared__ unsigned short As[BM * BK];
    __shared__ unsigned short Ws[BN * BK];
    int tid = threadIdx.x;
    int wid = tid >> 6, lane = tid & 63;
    int m0 = blockIdx.x * BM;
    int n0 = blockIdx.y * BN;

    f32x4 acc[2][4] = {};

    for (int k0 = 0; k0 < K; k0 += BK) {
        for (int i = tid; i < BM * (BK / 8); i += 256) {
            int row = i >> 3;
            int kk = (i & 7) * 8;
            int gr = m0 + row;
            short8v v = short8v{0, 0, 0, 0, 0, 0, 0, 0};
            if (gr < M) v = *reinterpret_cast<const short8v*>(&A[(size_t)gr * K + k0 + kk]);
            int byte = (kk * 2) ^ ((row & 7) << 4);
            *reinterpret_cast<short8v*>((char*)As + row * (BK * 2) + byte) = v;
        }
        for (int i = tid; i < BN * (BK / 8); i += 256) {
            int nrow = i >> 3;
            int kk = (i & 7) * 8;
            short8v v = *reinterpret_cast<const short8v*>(&WT[(size_t)(n0 + nrow) * K + k0 + kk]);
            int byte = (kk * 2) ^ ((nrow & 7) << 4);
            *reinterpret_cast<short8v*>((char*)Ws + nrow * (BK * 2) + byte) = v;
        }
        __syncthreads();
        #pragma unroll
        for (int kc = 0; kc < BK; kc += 32) {
            short8v afr[2], bfr[4];
            int kk = kc + (lane >> 4) * 8;
            #pragma unroll
            for (int mf = 0; mf < 2; mf++) {
                int row = wid * 32 + mf * 16 + (lane & 15);
                int byte = (kk * 2) ^ ((row & 7) << 4);
                afr[mf] = *reinterpret_cast<const short8v*>((char*)As + row * (BK * 2) + byte);
            }
            #pragma unroll
            for (int nf = 0; nf < 4; nf++) {
                int nrow = nf * 16 + (lane & 15);
                int byte = (kk * 2) ^ ((nrow & 7) << 4);
                bfr[nf] = *reinterpret_cast<const short8v*>((char*)Ws + nrow * (BK * 2) + byte);
            }
            #pragma unroll
            for (int mf = 0; mf < 2; mf++)
                #pragma unroll
                for (int nf = 0; nf < 4; nf++)
                    acc[mf][nf] = __builtin_amdgcn_mfma_f32_16x16x32_bf16(
                        afr[mf], bfr[nf], acc[mf][nf], 0, 0, 0);
        }
        __syncthreads();
    }
    #pragma unroll
    for (int mf = 0; mf < 2; mf++) {
        #pragma unroll
        for (int nf = 0; nf < 4; nf++) {
            #pragma unroll
            for (int r = 0; r < 4; r++) {
                int row = m0 + wid * 32 + mf * 16 + (lane >> 4) * 4 + r;
                int colg = n0 + nf * 16 + (lane & 15);
                if (row < M) {
                    float v = acc[mf][nf][r];
                    if (bias) v += bias[colg];
                    if constexpr (OBF)
                        ((unsigned short*)outp)[(size_t)row * C + colg] = f2bf(v);
                    else
                        ((float*)outp)[(size_t)row * C + colg] = v;
                }
            }
        }
    }
}

// ---------------- GCN layer1 prop: relu, bf16 out. wave per node, 1 ch/lane ----------------
__global__ __launch_bounds__(256) void gcn_prop1_kernel(const unsigned short* __restrict__ xw,
                                                        const float* __restrict__ dis,
                                                        const int* __restrict__ rowptr,
                                                        const int* __restrict__ col,
                                                        const float* __restrict__ bias,
                                                        unsigned short* __restrict__ outp, int n) {
    int wid = threadIdx.x >> 6, lane = threadIdx.x & 63;
    int node = blockIdx.x * 4 + wid;
    if (node >= n) return;
    float dd = dis[node];
    float acc = dd * bf2f(xw[(size_t)node * 64 + lane]);
    int b0 = rowptr[node], b1 = rowptr[node + 1];
    for (int i = b0; i < b1; i++) {
        int s = col[i];
        acc += dis[s] * bf2f(xw[(size_t)s * 64 + lane]);
    }
    float r = dd * acc + bias[lane];
    r = fmaxf(r, 0.f);
    outp[(size_t)node * 64 + lane] = f2bf(r);
}

// ---------------- GCN layer2 prop + LayerNorm -> catb[:, :128]. wave per node, 2 ch/lane ----------------
__global__ __launch_bounds__(256) void gcn_prop2_ln_kernel(const unsigned short* __restrict__ xw,
                                                           const float* __restrict__ dis,
                                                           const int* __restrict__ rowptr,
                                                           const int* __restrict__ col,
                                                           const float* __restrict__ bias,
                                                           const float* __restrict__ gw,
                                                           const float* __restrict__ gb,
                                                           unsigned short* __restrict__ catb, int n) {
    int wid = threadIdx.x >> 6, lane = threadIdx.x & 63;
    int node = blockIdx.x * 4 + wid;
    if (node >= n) return;
    float dd = dis[node];
    unsigned vs = *reinterpret_cast<const unsigned*>(&xw[(size_t)node * 128 + lane * 2]);
    float a0 = dd * bf2f((unsigned short)(vs & 0xFFFF));
    float a1 = dd * bf2f((unsigned short)(vs >> 16));
    int b0 = rowptr[node], b1 = rowptr[node + 1];
    for (int i = b0; i < b1; i++) {
        int s = col[i];
        float ds = dis[s];
        unsigned v = *reinterpret_cast<const unsigned*>(&xw[(size_t)s * 128 + lane * 2]);
        a0 += ds * bf2f((unsigned short)(v & 0xFFFF));
        a1 += ds * bf2f((unsigned short)(v >> 16));
    }
    float r0 = dd * a0 + bias[lane * 2];
    float r1 = dd * a1 + bias[lane * 2 + 1];
    float sm = r0 + r1, sq = r0 * r0 + r1 * r1;
    #pragma unroll
    for (int o = 1; o < 64; o <<= 1) { sm += __shfl_xor(sm, o, 64); sq += __shfl_xor(sq, o, 64); }
    float mu = sm * (1.f / 128.f);
    float var = sq * (1.f / 128.f) - mu * mu;
    float rs = rsqrtf(var + EPS);
    float o0 = (r0 - mu) * rs * gw[lane * 2] + gb[lane * 2];
    float o1 = (r1 - mu) * rs * gw[lane * 2 + 1] + gb[lane * 2 + 1];
    unsigned pk = (unsigned)f2bf(o0) | ((unsigned)f2bf(o1) << 16);
    *reinterpret_cast<unsigned*>(&catb[(size_t)node * 256 + lane * 2]) = pk;
}

// ---------------- alpha dots. wave per node ----------------
template<int HC>
__global__ __launch_bounds__(256) void alpha_kernel(const unsigned short* __restrict__ xh,
                                                    const float* __restrict__ a_src,
                                                    const float* __restrict__ a_dst,
                                                    float* __restrict__ as_, float* __restrict__ ad_, int n) {
    constexpr int PL = HC / 16;
    int wid = threadIdx.x >> 6, lane = threadIdx.x & 63;
    int node = blockIdx.x * 4 + wid;
    if (node >= n) return;
    int head = lane >> 4, cb = (lane & 15) * PL;
    const unsigned short* xr = xh + (size_t)node * (4 * HC) + lane * PL;
    float ps = 0.f, pd = 0.f;
    #pragma unroll
    for (int j = 0; j < PL; j++) {
        float v = bf2f(xr[j]);
        ps += v * a_src[head * HC + cb + j];
        pd += v * a_dst[head * HC + cb + j];
    }
    #pragma unroll
    for (int o = 1; o < 16; o <<= 1) { ps += __shfl_xor(ps, o, 64); pd += __shfl_xor(pd, o, 64); }
    if ((lane & 15) == 0) {
        as_[(size_t)node * 4 + head] = ps;
        ad_[(size_t)node * 4 + head] = pd;
    }
}

// ---------------- GAT layer1 prop: concat, ELU, bf16 out [n,256]. wave per node ----------------
__global__ __launch_bounds__(256) void gat_prop1_kernel(const unsigned short* __restrict__ xh,
                                                        const float* __restrict__ as_,
                                                        const float* __restrict__ ad_,
                                                        const int* __restrict__ rowptr,
                                                        const int* __restrict__ col,
                                                        const float* __restrict__ bias,
                                                        unsigned short* __restrict__ outp, int n) {
    constexpr int CAP = 96;
    __shared__ float ex[4][CAP][4];
    __shared__ int scol[4][CAP];
    int wid = threadIdx.x >> 6, lane = threadIdx.x & 63;
    int node = blockIdx.x * 4 + wid;
    if (node >= n) return;
    int b0 = rowptr[node];
    int cnt = rowptr[node + 1] - b0;
    float4 adv = *reinterpret_cast<const float4*>(&ad_[(size_t)node * 4]);
    float p0 = 0, p1 = 0, p2 = 0, p3 = 0;
    for (int i = lane; i <= cnt; i += 64) {
        int s = (i == cnt) ? node : col[b0 + i];
        float4 asv = *reinterpret_cast<const float4*>(&as_[(size_t)s * 4]);
        float e0 = asv.x + adv.x; e0 = e0 > 0.f ? e0 : NEG * e0; float x0 = __expf(e0);
        float e1 = asv.y + adv.y; e1 = e1 > 0.f ? e1 : NEG * e1; float x1 = __expf(e1);
        float e2 = asv.z + adv.z; e2 = e2 > 0.f ? e2 : NEG * e2; float x2 = __expf(e2);
        float e3 = asv.w + adv.w; e3 = e3 > 0.f ? e3 : NEG * e3; float x3 = __expf(e3);
        if (i < CAP) {
            ex[wid][i][0] = x0; ex[wid][i][1] = x1; ex[wid][i][2] = x2; ex[wid][i][3] = x3;
            scol[wid][i] = s;
        }
        p0 += x0; p1 += x1; p2 += x2; p3 += x3;
    }
    #pragma unroll
    for (int o = 1; o < 64; o <<= 1) {
        p0 += __shfl_xor(p0, o, 64); p1 += __shfl_xor(p1, o, 64);
        p2 += __shfl_xor(p2, o, 64); p3 += __shfl_xor(p3, o, 64);
    }
    __builtin_amdgcn_wave_barrier();
    int head = lane >> 4;
    float wsel = head == 0 ? 1.f / p0 : head == 1 ? 1.f / p1 : head == 2 ? 1.f / p2 : 1.f / p3;
    int coff = lane * 4;
    float fa0 = 0, fa1 = 0, fa2 = 0, fa3 = 0;
    for (int i = 0; i <= cnt; i++) {
        int s; float we;
        if (i < CAP) {
            s = scol[wid][i];
            we = ex[wid][i][head] * wsel;
        } else {
            s = (i == cnt) ? node : col[b0 + i];
            float4 asv = *reinterpret_cast<const float4*>(&as_[(size_t)s * 4]);
            float eh = head == 0 ? asv.x + adv.x : head == 1 ? asv.y + adv.y
                     : head == 2 ? asv.z + adv.z : asv.w + adv.w;
            eh = eh > 0.f ? eh : NEG * eh;
            we = __expf(eh) * wsel;
        }
        short4v v = *reinterpret_cast<const short4v*>(&xh[(size_t)s * 256 + coff]);
        fa0 += we * bf2f((unsigned short)v[0]);
        fa1 += we * bf2f((unsigned short)v[1]);
        fa2 += we * bf2f((unsigned short)v[2]);
        fa3 += we * bf2f((unsigned short)v[3]);
    }
    float r0 = fa0 + bias[coff];     r0 = r0 > 0.f ? r0 : __expf(r0) - 1.f;
    float r1 = fa1 + bias[coff + 1]; r1 = r1 > 0.f ? r1 : __expf(r1) - 1.f;
    float r2 = fa2 + bias[coff + 2]; r2 = r2 > 0.f ? r2 : __expf(r2) - 1.f;
    float r3 = fa3 + bias[coff + 3]; r3 = r3 > 0.f ? r3 : __expf(r3) - 1.f;
    short4v o4;
    o4[0] = (short)f2bf(r0); o4[1] = (short)f2bf(r1);
    o4[2] = (short)f2bf(r2); o4[3] = (short)f2bf(r3);
    *reinterpret_cast<short4v*>(&outp[(size_t)node * 256 + coff]) = o4;
}

// ---------------- GAT layer2 prop: head-mean + bias + LayerNorm -> catb[:, 128:]. wave per node ----------------
__global__ __launch_bounds__(256) void gat_prop2_ln_kernel(const unsigned short* __restrict__ xh,
                                                           const float* __restrict__ as_,
                                                           const float* __restrict__ ad_,
                                                           const int* __restrict__ rowptr,
                                                           const int* __restrict__ col,
                                                           const float* __restrict__ bias,
                                                           const float* __restrict__ gw,
                                                           const float* __restrict__ gb,
                                                           unsigned short* __restrict__ catb, int n) {
    constexpr int CAP = 96;
    __shared__ float ex[4][CAP][4];
    __shared__ int scol[4][CAP];
    int wid = threadIdx.x >> 6, lane = threadIdx.x & 63;
    int node = blockIdx.x * 4 + wid;
    if (node >= n) return;
    int b0 = rowptr[node];
    int cnt = rowptr[node + 1] - b0;
    float4 adv = *reinterpret_cast<const float4*>(&ad_[(size_t)node * 4]);
    float p0 = 0, p1 = 0, p2 = 0, p3 = 0;
    for (int i = lane; i <= cnt; i += 64) {
        int s = (i == cnt) ? node : col[b0 + i];
        float4 asv = *reinterpret_cast<const float4*>(&as_[(size_t)s * 4]);
        float e0 = asv.x + adv.x; e0 = e0 > 0.f ? e0 : NEG * e0; float x0 = __expf(e0);
        float e1 = asv.y + adv.y; e1 = e1 > 0.f ? e1 : NEG * e1; float x1 = __expf(e1);
        float e2 = asv.z + adv.z; e2 = e2 > 0.f ? e2 : NEG * e2; float x2 = __expf(e2);
        float e3 = asv.w + adv.w; e3 = e3 > 0.f ? e3 : NEG * e3; float x3 = __expf(e3);
        if (i < CAP) {
            ex[wid][i][0] = x0; ex[wid][i][1] = x1; ex[wid][i][2] = x2; ex[wid][i][3] = x3;
            scol[wid][i] = s;
        }
        p0 += x0; p1 += x1; p2 += x2; p3 += x3;
    }
    #pragma unroll
    for (int o = 1; o < 64; o <<= 1) {
        p0 += __shfl_xor(p0, o, 64); p1 += __shfl_xor(p1, o, 64);
        p2 += __shfl_xor(p2, o, 64); p3 += __shfl_xor(p3, o, 64);
    }
    __builtin_amdgcn_wave_barrier();
    int head = lane >> 4;
    float wsel = head == 0 ? 0.25f / p0 : head == 1 ? 0.25f / p1 : head == 2 ? 0.25f / p2 : 0.25f / p3;
    int cw = (lane & 15) * 8;
    float facc[8] = {0, 0, 0, 0, 0, 0, 0, 0};
    for (int i = 0; i <= cnt; i++) {
        int s; float we;
        if (i < CAP) {
            s = scol[wid][i];
            we = ex[wid][i][head] * wsel;
        } else {
            s = (i == cnt) ? node : col[b0 + i];
            float4 asv = *reinterpret_cast<const float4*>(&as_[(size_t)s * 4]);
            float eh = head == 0 ? asv.x + adv.x : head == 1 ? asv.y + adv.y
                     : head == 2 ? asv.z + adv.z : asv.w + adv.w;
            eh = eh > 0.f ? eh : NEG * eh;
            we = __expf(eh) * wsel;
        }
        short8v v = *reinterpret_cast<const short8v*>(&xh[(size_t)s * 512 + lane * 8]);
        #pragma unroll
        for (int j = 0; j < 8; j++) facc[j] += we * bf2f((unsigned short)v[j]);
    }
    #pragma unroll
    for (int j = 0; j < 8; j++) {
        facc[j] += __shfl_xor(facc[j], 16, 64);
        facc[j] += __shfl_xor(facc[j], 32, 64);
        facc[j] += bias[cw + j];
    }
    float sm = 0, sq = 0;
    #pragma unroll
    for (int j = 0; j < 8; j++) { sm += facc[j]; sq += facc[j] * facc[j]; }
    #pragma unroll
    for (int o = 1; o < 16; o <<= 1) { sm += __shfl_xor(sm, o, 64); sq += __shfl_xor(sq, o, 64); }
    float mu = sm * (1.f / 128.f);
    float var = sq * (1.f / 128.f) - mu * mu;
    float rs = rsqrtf(var + EPS);
    if (lane < 16) {
        short8v o8;
        #pragma unroll
        for (int j = 0; j < 8; j++)
            o8[j] = (short)f2bf((facc[j] - mu) * rs * gw[cw + j] + gb[cw + j]);
        *reinterpret_cast<short8v*>(&catb[(size_t)node * 256 + 128 + cw]) = o8;
    }
}

// ---------------- launch ----------------
extern "C" void kernel_launch(void* const* d_in, const int* in_sizes, int n_in,
                              void* d_out, int out_size, void* d_ws, size_t ws_size,
                              hipStream_t stream) {
    const float* x      = (const float*)d_in[0];
    const int*   ei     = (const int*)d_in[1];
    const float* W_gcn1 = (const float*)d_in[2];
    const float* b_gcn1 = (const float*)d_in[3];
    const float* W_gcn2 = (const float*)d_in[4];
    const float* b_gcn2 = (const float*)d_in[5];
    const float* W_gat1 = (const float*)d_in[6];
    const float* a_src1 = (const float*)d_in[7];
    const float* a_dst1 = (const float*)d_in[8];
    const float* b_gat1 = (const float*)d_in[9];
    const float* W_gat2 = (const float*)d_in[10];
    const float* a_src2 = (const float*)d_in[11];
    const float* a_dst2 = (const float*)d_in[12];
    const float* b_gat2 = (const float*)d_in[13];
    const float* g_gcn  = (const float*)d_in[14];
    const float* bt_gcn = (const float*)d_in[15];
    const float* g_gat  = (const float*)d_in[16];
    const float* bt_gat = (const float*)d_in[17];
    const float* W_fuse = (const float*)d_in[18];
    const float* b_fuse = (const float*)d_in[19];
    float* out = (float*)d_out;

    const int n = in_sizes[0] / 128;
    const int E = in_sizes[1] / 2;

    char* ws = (char*)d_ws;
    size_t off = 0;
    auto alloc = [&](size_t bytes) -> char* {
        char* p = ws + off;
        off += (bytes + 255) & ~(size_t)255;
        return p;
    };
    int*   cnt      = (int*)alloc((size_t)n * 4);
    int*   rowptr   = (int*)alloc((size_t)(n + 1) * 4);
    int*   cursor   = (int*)alloc((size_t)n * 4);
    int*   col      = (int*)alloc((size_t)E * 4);
    int*   partials = (int*)alloc(64 * 4);
    float* dis      = (float*)alloc((size_t)n * 4);
    float* as_      = (float*)alloc((size_t)n * 16);
    float* ad_      = (float*)alloc((size_t)n * 16);
    unsigned short* xb   = (unsigned short*)alloc((size_t)n * 128 * 2);
    unsigned short* WT1  = (unsigned short*)alloc(8192 * 2);
    unsigned short* WT2  = (unsigned short*)alloc(8192 * 2);
    unsigned short* WT3  = (unsigned short*)alloc(32768 * 2);
    unsigned short* WT4  = (unsigned short*)alloc(131072 * 2);
    unsigned short* WT5  = (unsigned short*)alloc(32768 * 2);
    unsigned short* xw1b = (unsigned short*)alloc((size_t)n * 64 * 2);
    unsigned short* hb   = (unsigned short*)alloc((size_t)n * 64 * 2);
    unsigned short* xw2b = (unsigned short*)alloc((size_t)n * 128 * 2);
    unsigned short* xh1b = (unsigned short*)alloc((size_t)n * 256 * 2);
    unsigned short* g1b  = (unsigned short*)alloc((size_t)n * 256 * 2);
    unsigned short* xh2b = (unsigned short*)alloc((size_t)n * 512 * 2);
    unsigned short* catb = (unsigned short*)alloc((size_t)n * 256 * 2);

    const int nb = (n + 1023) / 1024;   // 49 for n=50000 (<=64)

    // CSR build + converts
    hipMemsetAsync(cnt, 0, (size_t)n * 4, stream);
    count_kernel<<<(E + 255) / 256, 256, 0, stream>>>(ei, cnt, E);
    partial_kernel<<<nb, 256, 0, stream>>>(cnt, partials, n);
    scanp_kernel<<<1, 64, 0, stream>>>(partials, nb);
    scan2_kernel<<<nb, 256, 0, stream>>>(cnt, partials, rowptr, cursor, dis, n, E);
    fill_kernel<<<(E + 255) / 256, 256, 0, stream>>>(ei, cursor, col, E);
    convert_x_kernel<<<(n * 32 + 255) / 256, 256, 0, stream>>>(x, xb, n * 32);
    convert_weights_kernel<<<(212992 + 255) / 256, 256, 0, stream>>>(
        W_gcn1, W_gcn2, W_gat1, W_gat2, W_fuse, WT1, WT2, WT3, WT4, WT5);

    int gm = (n + 127) / 128;
    int gn4 = (n + 3) / 4;

    // GCN branch
    mfma_gemm<128, 64, true><<<dim3(gm, 1), 256, 0, stream>>>(xb, WT1, nullptr, xw1b, n);
    gcn_prop1_kernel<<<gn4, 256, 0, stream>>>(xw1b, dis, rowptr, col, b_gcn1, hb, n);
    mfma_gemm<64, 128, true><<<dim3(gm, 2), 256, 0, stream>>>(hb, WT2, nullptr, xw2b, n);
    gcn_prop2_ln_kernel<<<gn4, 256, 0, stream>>>(xw2b, dis, rowptr, col, b_gcn2, g_gcn, bt_gcn, catb, n);

    // GAT branch
    mfma_gemm<128, 256, true><<<dim3(gm, 4), 256, 0, stream>>>(xb, WT3, nullptr, xh1b, n);
    alpha_kernel<64><<<gn4, 256, 0, stream>>>(xh1b, a_src1, a_dst1, as_, ad_, n);
    gat_prop1_kernel<<<gn4, 256, 0, stream>>>(xh1b, as_, ad_, rowptr, col, b_gat1, g1b, n);
    mfma_gemm<256, 512, true><<<dim3(gm, 8), 256, 0, stream>>>(g1b, WT4, nullptr, xh2b, n);
    alpha_kernel<128><<<gn4, 256, 0, stream>>>(xh2b, a_src2, a_dst2, as_, ad_, n);
    gat_prop2_ln_kernel<<<gn4, 256, 0, stream>>>(xh2b, as_, ad_, rowptr, col, b_gat2, g_gat, bt_gat, catb, n);

    // fuse
    mfma_gemm<256, 128, false><<<dim3(gm, 2), 256, 0, stream>>>(catb, WT5, b_fuse, out, n);
}